// Round 8
// baseline (576.247 us; speedup 1.0000x reference)
//
#include <hip/hip_runtime.h>
#include <hip/hip_bf16.h>
#include <cstdint>
#include <cstddef>

// Problem constants: data (4,8,4096,3) -> 32 batches x 4096 points
#define BT 32
#define N1 4096
#define S1 256
#define S2 128
#define KNB 32

typedef __attribute__((ext_vector_type(8))) short short8;   // 8 bf16 in 4 VGPRs
typedef __attribute__((ext_vector_type(4))) float f32x4;

__device__ __forceinline__ float sqdist(float ax, float ay, float az,
                                        float bx, float by, float bz) {
    // exact replication of sum((a-b)**2, axis=-1): mul then left-to-right add, NO fma
    float dx = __fsub_rn(ax, bx), dy = __fsub_rn(ay, by), dz = __fsub_rn(az, bz);
    return __fadd_rn(__fadd_rn(__fmul_rn(dx, dx), __fmul_rn(dy, dy)), __fmul_rn(dz, dz));
}

// bf16 round-to-nearest-even (values here are finite)
__device__ __forceinline__ unsigned short f2bf(float f) {
    unsigned u = __float_as_uint(f);
    return (unsigned short)((u + 0x7FFFu + ((u >> 16) & 1u)) >> 16);
}
__device__ __forceinline__ float bf2f(unsigned short h) {
    return __uint_as_float(((unsigned)h) << 16);
}

// pack (value, index) for argmax-with-first-index-tie-break: distances >= 0 so float
// bits are monotonic as uint; on equal value, larger ~idx == smaller idx wins.
__device__ __forceinline__ unsigned long long packvi(float v, int idx) {
    return ((unsigned long long)__float_as_uint(v) << 32) | (unsigned)(~idx);
}

// DPP row-rotate max for u64 (rotate within 16-lane rows; commutative reduce)
template <int CTRL>
__device__ __forceinline__ unsigned long long dppmax(unsigned long long v) {
    int lo = (int)(unsigned)(v & 0xFFFFFFFFull);
    int hi = (int)(unsigned)(v >> 32);
    int lo2 = __builtin_amdgcn_update_dpp(0, lo, CTRL, 0xF, 0xF, false);
    int hi2 = __builtin_amdgcn_update_dpp(0, hi, CTRL, 0xF, 0xF, false);
    unsigned long long o = ((unsigned long long)(unsigned)hi2 << 32) | (unsigned)lo2;
    return o > v ? o : v;
}
#define ROR1 0x121
#define ROR2 0x122
#define ROR4 0x124
#define ROR8 0x128

// ---------------- FPS module 1: N=4096 -> 256, one block/batch, 256 threads ----------
// 4 waves (1/SIMD). Reduce: 4 in-row DPP -> 16 LDS slots -> 4 in-row DPP. No shfl.
__global__ __launch_bounds__(256) void fps1_kernel(const float* __restrict__ xyz,
                                                   float* __restrict__ nxz) {
    const int b = blockIdx.x, tid = threadIdx.x;
    const int lane = tid & 63, wv = tid >> 6;      // 4 waves
    const float* X = xyz + (size_t)b * (N1 * 3);
    __shared__ float4 s4[N1];                      // 64 KB
    __shared__ unsigned long long slots[2][16];
    __shared__ float hist[S1 * 3];
    float px[16], py[16], pz[16], md[16];
    int bidx[16];
#pragma unroll
    for (int j = 0; j < 16; ++j) {
        int i = tid + 256 * j;
        float x = X[i * 3 + 0], y = X[i * 3 + 1], z = X[i * 3 + 2];
        s4[i] = make_float4(x, y, z, 0.f);
        px[j] = x; py[j] = y; pz[j] = z;
        md[j] = 1e10f;
        bidx[j] = i;
    }
    if (tid == 0) { hist[0] = X[0]; hist[1] = X[1]; hist[2] = X[2]; }
    __syncthreads();
    float4 c0 = s4[0];
    float lx = c0.x, ly = c0.y, lz = c0.z;
    for (int t = 1; t < S1; ++t) {
        float bv = -1.0f; int bi = 0;
#pragma unroll
        for (int j = 0; j < 16; ++j) {
            float d = sqdist(px[j], py[j], pz[j], lx, ly, lz);
            float m = fminf(md[j], d);
            md[j] = m;
            if (m > bv) { bv = m; bi = bidx[j]; }   // ascending flat idx: first max kept
        }
        unsigned long long best = packvi(bv, bi);
        best = dppmax<ROR1>(best);
        best = dppmax<ROR2>(best);
        best = dppmax<ROR4>(best);
        best = dppmax<ROR8>(best);                  // row (16-lane) max
        if ((lane & 15) == 0) slots[t & 1][wv * 4 + (lane >> 4)] = best;
        __syncthreads();
        unsigned long long w = slots[t & 1][lane & 15];
        w = dppmax<ROR1>(w);
        w = dppmax<ROR2>(w);
        w = dppmax<ROR4>(w);
        w = dppmax<ROR8>(w);
        int vi = (int)(~(unsigned)w);
        float4 c = s4[vi];
        lx = c.x; ly = c.y; lz = c.z;
        if (tid == 0) { hist[t * 3 + 0] = lx; hist[t * 3 + 1] = ly; hist[t * 3 + 2] = lz; }
    }
    __syncthreads();
    for (int u = tid; u < S1 * 3; u += 256) nxz[(size_t)b * S1 * 3 + u] = hist[u];
}

// ---------------- FPS module 2: N=256 -> 128, ONE WAVE per batch ----------
__global__ __launch_bounds__(64) void fps2_kernel(const float* __restrict__ xyz1,
                                                  float* __restrict__ nxz2) {
    const int b = blockIdx.x, lane = threadIdx.x;
    const float* X = xyz1 + (size_t)b * (S1 * 3);
    __shared__ float4 s4[S1];
    float px[4], py[4], pz[4], md[4];
    int bidx[4];
#pragma unroll
    for (int j = 0; j < 4; ++j) {
        int i = lane + 64 * j;
        float x = X[i * 3 + 0], y = X[i * 3 + 1], z = X[i * 3 + 2];
        s4[i] = make_float4(x, y, z, 0.f);
        px[j] = x; py[j] = y; pz[j] = z;
        md[j] = 1e10f;
        bidx[j] = i;
    }
    if (lane == 0) {
        nxz2[(size_t)b * S2 * 3 + 0] = X[0];
        nxz2[(size_t)b * S2 * 3 + 1] = X[1];
        nxz2[(size_t)b * S2 * 3 + 2] = X[2];
    }
    // single wave: LDS writes above are wave-synchronous
    float4 cc = s4[0];
    float lx = cc.x, ly = cc.y, lz = cc.z;
    for (int t = 1; t < S2; ++t) {
        float bv = -1.0f; int bi = 0;
#pragma unroll
        for (int j = 0; j < 4; ++j) {
            float d = sqdist(px[j], py[j], pz[j], lx, ly, lz);
            float m = fminf(md[j], d);
            md[j] = m;
            if (m > bv) { bv = m; bi = bidx[j]; }
        }
        unsigned long long best = packvi(bv, bi);
        best = dppmax<ROR1>(best);
        best = dppmax<ROR2>(best);
        best = dppmax<ROR4>(best);
        best = dppmax<ROR8>(best);
        { unsigned long long o = __shfl_xor(best, 16); best = o > best ? o : best; }
        { unsigned long long o = __shfl_xor(best, 32); best = o > best ? o : best; }
        int vi = (int)(~(unsigned)best);
        float4 c = s4[vi];
        lx = c.x; ly = c.y; lz = c.z;
        if (lane == 0) {
            float* dst = nxz2 + ((size_t)b * S2 + t) * 3;
            dst[0] = lx; dst[1] = ly; dst[2] = lz;
        }
    }
}

// ---------------- Weight conversion: fp32 -> bf16 arena, K padded to x64 ----------------
//  w11b@0      64x64   | w12b@4096  128x64 | w20p@12288 128x192 (PERMUTED: feat-first)
//  w21b@36864  128x128 | w22b@53248 256x128| w30b@86016 256x320 (259->320)
//  w31b@167936 512x256 | w32b@299008 1024x512  total 823296
__global__ __launch_bounds__(256) void wconv_kernel(
    const float* __restrict__ w11, const float* __restrict__ w12,
    const float* __restrict__ w20, const float* __restrict__ w21,
    const float* __restrict__ w22, const float* __restrict__ w30,
    const float* __restrict__ w31, const float* __restrict__ w32,
    unsigned short* __restrict__ wb) {
    int u = blockIdx.x * 256 + threadIdx.x;
    if (u >= 823296) return;
    const float* src; int base, Kp, Ko; bool perm20 = false;
    if      (u < 4096)   { src = w11; base = 0;      Kp = 64;  Ko = 64;  }
    else if (u < 12288)  { src = w12; base = 4096;   Kp = 64;  Ko = 64;  }
    else if (u < 36864)  { src = w20; base = 12288;  Kp = 192; Ko = 131; perm20 = true; }
    else if (u < 53248)  { src = w21; base = 36864;  Kp = 128; Ko = 128; }
    else if (u < 86016)  { src = w22; base = 53248;  Kp = 128; Ko = 128; }
    else if (u < 167936) { src = w30; base = 86016;  Kp = 320; Ko = 259; }
    else if (u < 299008) { src = w31; base = 167936; Kp = 256; Ko = 256; }
    else                 { src = w32; base = 299008; Kp = 512; Ko = 512; }
    int local = u - base;
    int n = local / Kp, k = local - n * Kp;
    float v;
    if (perm20) {
        int ksrc = (k < 128) ? (k + 3) : ((k < 131) ? (k - 128) : -1);
        v = (ksrc >= 0) ? src[(size_t)n * 131 + ksrc] : 0.f;
    } else {
        v = (k < Ko) ? src[(size_t)n * Ko + k] : 0.f;
    }
    wb[u] = f2bf(v);
}

// ---------------- Module 1 fused: ballq + gather + L0(VALU) + L1 + L2 MFMA + pool ------
// 2048 blocks x 256 thr; block = 128 rows = 4 centers; wave w does center w's ball query.
__global__ __launch_bounds__(256) void m1_kernel(
    const float* __restrict__ xyz, const float* __restrict__ nxz,
    const float* __restrict__ w10, const float* __restrict__ b10,
    const unsigned short* __restrict__ w11b, const float* __restrict__ b11,
    const unsigned short* __restrict__ w12b, const float* __restrict__ b12,
    unsigned short* __restrict__ f1) {
    constexpr int AP = 72;
    __shared__ __align__(16) unsigned short As[128 * AP];
    __shared__ __align__(16) unsigned short Hs[128 * AP];
    __shared__ __align__(16) unsigned short Bs[128 * AP];
    __shared__ float sxyz[128 * 3];
    __shared__ int Gl[4][KNB];
    const int t = threadIdx.x;
    const int lane = t & 63, w = t >> 6;
    const int r16 = lane & 15, q = lane >> 4;
    const int m0 = blockIdx.x * 128;

    // stage w11 (64 rows x 64) — independent of ballq
    for (int c = t; c < 64 * 8; c += 256) {
        int row = c >> 3, ch = c & 7;
        *(short8*)&Bs[row * AP + ch * 8] = *(const short8*)&w11b[row * 64 + ch * 8];
    }
    // ball query: wave w -> center (m0>>5)+w
    {
        const int cs = (m0 >> 5) + w;
        const int b = cs >> 8;
        const float* Xb = xyz + (size_t)b * (N1 * 3);
        const float* C = nxz + (size_t)cs * 3;
        const float cx = C[0], cy = C[1], cz = C[2];
        const float r2 = (float)(0.2 * 0.2);
        int cnt = 0, first = 0;
        bool found = false;
        for (int j0 = 0; j0 < N1 && cnt < KNB; j0 += 64) {
            int j = j0 + lane;
            float d2 = sqdist(cx, cy, cz, Xb[j * 3 + 0], Xb[j * 3 + 1], Xb[j * 3 + 2]);
            bool hit = d2 < r2;
            unsigned long long mask = __ballot(hit);
            if (!found && mask) { first = j0 + __builtin_ctzll(mask); found = true; }
            if (hit) {
                int pos = cnt + __popcll(mask & ((1ull << lane) - 1ull));
                if (pos < KNB) Gl[w][pos] = j;
            }
            cnt += __popcll(mask);
        }
        if (cnt < KNB) {
            int pad = found ? first : 0;
            if (lane >= cnt && lane < KNB) Gl[w][lane] = pad;
        }
    }
    __syncthreads();
    if (t < 128) {
        int row = m0 + t, bs = row >> 5, b = bs >> 8;
        int j = Gl[t >> 5][t & 31];
        const float* P = xyz + ((size_t)b * N1 + j) * 3;
        const float* Cc = nxz + (size_t)bs * 3;
        sxyz[t * 3 + 0] = P[0] - Cc[0];
        sxyz[t * 3 + 1] = P[1] - Cc[1];
        sxyz[t * 3 + 2] = P[2] - Cc[2];
    }
    __syncthreads();
    {
        const int r = t >> 1, half = (t & 1) * 32;
        const float x = sxyz[r * 3 + 0], y = sxyz[r * 3 + 1], z = sxyz[r * 3 + 2];
        unsigned short tmp[32];
#pragma unroll
        for (int o = 0; o < 32; ++o) {
            int oo = half + o;
            float acc = b10[oo];
            acc = fmaf(x, w10[oo * 3 + 0], acc);
            acc = fmaf(y, w10[oo * 3 + 1], acc);
            acc = fmaf(z, w10[oo * 3 + 2], acc);
            tmp[o] = f2bf(fmaxf(acc, 0.f));
        }
#pragma unroll
        for (int c2 = 0; c2 < 4; ++c2)
            *(short8*)&As[r * AP + half + c2 * 8] = *(short8*)&tmp[c2 * 8];
    }
    __syncthreads();
    {
        f32x4 acc[2][4];
#pragma unroll
        for (int i = 0; i < 2; ++i)
#pragma unroll
            for (int j = 0; j < 4; ++j) acc[i][j] = (f32x4){0.f, 0.f, 0.f, 0.f};
#pragma unroll
        for (int kk = 0; kk < 64; kk += 32) {
            short8 a0 = *(const short8*)&As[(w * 32 + r16) * AP + kk + q * 8];
            short8 a1 = *(const short8*)&As[(w * 32 + 16 + r16) * AP + kk + q * 8];
#pragma unroll
            for (int j = 0; j < 4; ++j) {
                short8 bf = *(const short8*)&Bs[(j * 16 + r16) * AP + kk + q * 8];
                acc[0][j] = __builtin_amdgcn_mfma_f32_16x16x32_bf16(a0, bf, acc[0][j], 0, 0, 0);
                acc[1][j] = __builtin_amdgcn_mfma_f32_16x16x32_bf16(a1, bf, acc[1][j], 0, 0, 0);
            }
        }
#pragma unroll
        for (int i = 0; i < 2; ++i)
#pragma unroll
            for (int j = 0; j < 4; ++j) {
                int col = j * 16 + r16;
                float bv = b11[col];
#pragma unroll
                for (int r = 0; r < 4; ++r) {
                    int row = w * 32 + i * 16 + q * 4 + r;
                    Hs[row * AP + col] = f2bf(fmaxf(acc[i][j][r] + bv, 0.f));
                }
            }
    }
    __syncthreads();
    for (int c = t; c < 128 * 8; c += 256) {
        int row = c >> 3, ch = c & 7;
        *(short8*)&Bs[row * AP + ch * 8] = *(const short8*)&w12b[row * 64 + ch * 8];
    }
    __syncthreads();
    {
        f32x4 acc[2][8];
#pragma unroll
        for (int i = 0; i < 2; ++i)
#pragma unroll
            for (int j = 0; j < 8; ++j) acc[i][j] = (f32x4){0.f, 0.f, 0.f, 0.f};
#pragma unroll
        for (int kk = 0; kk < 64; kk += 32) {
            short8 a0 = *(const short8*)&Hs[(w * 32 + r16) * AP + kk + q * 8];
            short8 a1 = *(const short8*)&Hs[(w * 32 + 16 + r16) * AP + kk + q * 8];
#pragma unroll
            for (int j = 0; j < 8; ++j) {
                short8 bf = *(const short8*)&Bs[(j * 16 + r16) * AP + kk + q * 8];
                acc[0][j] = __builtin_amdgcn_mfma_f32_16x16x32_bf16(a0, bf, acc[0][j], 0, 0, 0);
                acc[1][j] = __builtin_amdgcn_mfma_f32_16x16x32_bf16(a1, bf, acc[1][j], 0, 0, 0);
            }
        }
#pragma unroll
        for (int j = 0; j < 8; ++j) {
            int col = j * 16 + r16;
            float bv = b12[col];
            float mv = 0.f;
#pragma unroll
            for (int i = 0; i < 2; ++i)
#pragma unroll
                for (int r = 0; r < 4; ++r)
                    mv = fmaxf(mv, acc[i][j][r] + bv);
            mv = fmaxf(mv, __shfl_xor(mv, 16));
            mv = fmaxf(mv, __shfl_xor(mv, 32));
            if (q == 0)
                f1[(size_t)((m0 >> 5) + w) * 128 + col] = f2bf(mv);
        }
    }
}

// ---------------- Module 2 fused: ballq + gather + L0(192) + L1(128) + L2(256)+pool ----
__global__ __launch_bounds__(256) void m2_kernel(
    const float* __restrict__ xyz1, const float* __restrict__ nxz2,
    const unsigned short* __restrict__ f1,
    const unsigned short* __restrict__ w20p, const float* __restrict__ b20,
    const unsigned short* __restrict__ w21b, const float* __restrict__ b21,
    const unsigned short* __restrict__ w22b, const float* __restrict__ b22,
    unsigned short* __restrict__ f2) {
    constexpr int AP = 72, HP = 136;
    __shared__ __align__(16) unsigned short smem[36864];   // 72 KB
    unsigned short* R1 = smem;
    unsigned short* R2 = smem + 18432;
    unsigned short* As = R1;
    unsigned short* Bs = R1 + 9216;
    unsigned short* H1 = R2;
    unsigned short* H2 = R1;
    unsigned short* Bs2 = R2;
    __shared__ int ribase[128];
    __shared__ unsigned short sxb[128 * 3];
    __shared__ int Gl[4][KNB];
    const int t = threadIdx.x;
    const int lane = t & 63, w = t >> 6;
    const int r16 = lane & 15, q = lane >> 4;
    const int m0 = blockIdx.x * 128;

    // ball query: wave w -> center (m0>>5)+w over S1=256 pts
    {
        const int cs = (m0 >> 5) + w;
        const int b = cs >> 7;
        const float* Xb = xyz1 + (size_t)b * (S1 * 3);
        const float* C = nxz2 + (size_t)cs * 3;
        const float cx = C[0], cy = C[1], cz = C[2];
        const float r2 = (float)(0.4 * 0.4);
        int cnt = 0, first = 0;
        bool found = false;
        for (int j0 = 0; j0 < S1 && cnt < KNB; j0 += 64) {
            int j = j0 + lane;
            float d2 = sqdist(cx, cy, cz, Xb[j * 3 + 0], Xb[j * 3 + 1], Xb[j * 3 + 2]);
            bool hit = d2 < r2;
            unsigned long long mask = __ballot(hit);
            if (!found && mask) { first = j0 + __builtin_ctzll(mask); found = true; }
            if (hit) {
                int pos = cnt + __popcll(mask & ((1ull << lane) - 1ull));
                if (pos < KNB) Gl[w][pos] = j;
            }
            cnt += __popcll(mask);
        }
        if (cnt < KNB) {
            int pad = found ? first : 0;
            if (lane >= cnt && lane < KNB) Gl[w][lane] = pad;
        }
    }
    __syncthreads();
    if (t < 128) {
        int row = m0 + t, bs = row >> 5, b = bs >> 7;
        int j = Gl[t >> 5][t & 31];
        ribase[t] = (b * 256 + j) * 128;
        const float* P = xyz1 + ((size_t)b * S1 + j) * 3;
        const float* Cc = nxz2 + (size_t)bs * 3;
        sxb[t * 3 + 0] = f2bf(P[0] - Cc[0]);
        sxb[t * 3 + 1] = f2bf(P[1] - Cc[1]);
        sxb[t * 3 + 2] = f2bf(P[2] - Cc[2]);
    }
    __syncthreads();

    // ---- L0: K=192 (3 tiles), N=128 ----
    f32x4 acc[2][8];
#pragma unroll
    for (int i = 0; i < 2; ++i)
#pragma unroll
        for (int j = 0; j < 8; ++j) acc[i][j] = (f32x4){0.f, 0.f, 0.f, 0.f};
    for (int kt = 0; kt < 3; ++kt) {
        const int k0 = kt * 64;
        if (kt < 2) {
            for (int c = t; c < 128 * 8; c += 256) {
                int row = c >> 3, ch = c & 7;
                *(short8*)&As[row * AP + ch * 8] =
                    *(const short8*)&f1[(size_t)ribase[row] + k0 + ch * 8];
            }
        } else {
            for (int c = t; c < 128 * 8; c += 256) {
                int row = c >> 3, ch = c & 7;
                short8 v = (short8){0, 0, 0, 0, 0, 0, 0, 0};
                if (ch == 0) {
                    v[0] = (short)sxb[row * 3 + 0];
                    v[1] = (short)sxb[row * 3 + 1];
                    v[2] = (short)sxb[row * 3 + 2];
                }
                *(short8*)&As[row * AP + ch * 8] = v;
            }
        }
        for (int c = t; c < 128 * 8; c += 256) {
            int row = c >> 3, ch = c & 7;
            *(short8*)&Bs[row * AP + ch * 8] =
                *(const short8*)&w20p[(size_t)row * 192 + k0 + ch * 8];
        }
        __syncthreads();
#pragma unroll
        for (int kk = 0; kk < 64; kk += 32) {
            short8 a0 = *(const short8*)&As[(w * 32 + r16) * AP + kk + q * 8];
            short8 a1 = *(const short8*)&As[(w * 32 + 16 + r16) * AP + kk + q * 8];
#pragma unroll
            for (int j = 0; j < 8; ++j) {
                short8 bf = *(const short8*)&Bs[(j * 16 + r16) * AP + kk + q * 8];
                acc[0][j] = __builtin_amdgcn_mfma_f32_16x16x32_bf16(a0, bf, acc[0][j], 0, 0, 0);
                acc[1][j] = __builtin_amdgcn_mfma_f32_16x16x32_bf16(a1, bf, acc[1][j], 0, 0, 0);
            }
        }
        __syncthreads();
    }
#pragma unroll
    for (int i = 0; i < 2; ++i)
#pragma unroll
        for (int j = 0; j < 8; ++j) {
            int col = j * 16 + r16;
            float bv = b20[col];
#pragma unroll
            for (int r = 0; r < 4; ++r) {
                int row = w * 32 + i * 16 + q * 4 + r;
                H1[row * HP + col] = f2bf(fmaxf(acc[i][j][r] + bv, 0.f));
            }
        }
    __syncthreads();

    // ---- L1: K=128 (2 tiles), N=128 ----
#pragma unroll
    for (int i = 0; i < 2; ++i)
#pragma unroll
        for (int j = 0; j < 8; ++j) acc[i][j] = (f32x4){0.f, 0.f, 0.f, 0.f};
    for (int kt = 0; kt < 2; ++kt) {
        const int k0 = kt * 64;
        for (int c = t; c < 128 * 8; c += 256) {
            int row = c >> 3, ch = c & 7;
            *(short8*)&As[row * AP + ch * 8] =
                *(const short8*)&w21b[(size_t)row * 128 + k0 + ch * 8];
        }
        __syncthreads();
#pragma unroll
        for (int kk = 0; kk < 64; kk += 32) {
            short8 a0 = *(const short8*)&H1[(w * 32 + r16) * HP + k0 + kk + q * 8];
            short8 a1 = *(const short8*)&H1[(w * 32 + 16 + r16) * HP + k0 + kk + q * 8];
#pragma unroll
            for (int j = 0; j < 8; ++j) {
                short8 bf = *(const short8*)&As[(j * 16 + r16) * AP + kk + q * 8];
                acc[0][j] = __builtin_amdgcn_mfma_f32_16x16x32_bf16(a0, bf, acc[0][j], 0, 0, 0);
                acc[1][j] = __builtin_amdgcn_mfma_f32_16x16x32_bf16(a1, bf, acc[1][j], 0, 0, 0);
            }
        }
        __syncthreads();
    }
#pragma unroll
    for (int i = 0; i < 2; ++i)
#pragma unroll
        for (int j = 0; j < 8; ++j) {
            int col = j * 16 + r16;
            float bv = b21[col];
#pragma unroll
            for (int r = 0; r < 4; ++r) {
                int row = w * 32 + i * 16 + q * 4 + r;
                H2[row * HP + col] = f2bf(fmaxf(acc[i][j][r] + bv, 0.f));
            }
        }
    __syncthreads();

    // ---- L2: K=128 (2 tiles), N=256 + pool ----
    f32x4 acc2[2][16];
#pragma unroll
    for (int i = 0; i < 2; ++i)
#pragma unroll
        for (int j = 0; j < 16; ++j) acc2[i][j] = (f32x4){0.f, 0.f, 0.f, 0.f};
    for (int kt = 0; kt < 2; ++kt) {
        const int k0 = kt * 64;
        for (int c = t; c < 256 * 8; c += 256) {
            int row = c >> 3, ch = c & 7;
            *(short8*)&Bs2[row * AP + ch * 8] =
                *(const short8*)&w22b[(size_t)row * 128 + k0 + ch * 8];
        }
        __syncthreads();
#pragma unroll
        for (int kk = 0; kk < 64; kk += 32) {
            short8 a0 = *(const short8*)&H2[(w * 32 + r16) * HP + k0 + kk + q * 8];
            short8 a1 = *(const short8*)&H2[(w * 32 + 16 + r16) * HP + k0 + kk + q * 8];
#pragma unroll
            for (int j = 0; j < 16; ++j) {
                short8 bf = *(const short8*)&Bs2[(j * 16 + r16) * AP + kk + q * 8];
                acc2[0][j] = __builtin_amdgcn_mfma_f32_16x16x32_bf16(a0, bf, acc2[0][j], 0, 0, 0);
                acc2[1][j] = __builtin_amdgcn_mfma_f32_16x16x32_bf16(a1, bf, acc2[1][j], 0, 0, 0);
            }
        }
        __syncthreads();
    }
#pragma unroll
    for (int j = 0; j < 16; ++j) {
        int col = j * 16 + r16;
        float bv = b22[col];
        float mv = 0.f;
#pragma unroll
        for (int i = 0; i < 2; ++i)
#pragma unroll
            for (int r = 0; r < 4; ++r)
                mv = fmaxf(mv, acc2[i][j][r] + bv);
        mv = fmaxf(mv, __shfl_xor(mv, 16));
        mv = fmaxf(mv, __shfl_xor(mv, 32));
        if (q == 0)
            f2[(size_t)((m0 >> 5) + w) * 256 + col] = f2bf(mv);
    }
}

// ---------------- Gather 3: bf16, K padded 259->320 ----------------
__global__ __launch_bounds__(256) void gather3_kernel(const float* __restrict__ nxz2,
                                                      const unsigned short* __restrict__ f2,
                                                      unsigned short* __restrict__ Xg) {
    int u = blockIdx.x * 256 + threadIdx.x;          // < 4096*320
    int r = u / 320, c = u - r * 320;
    unsigned short v;
    if (c < 3)        v = f2bf(nxz2[(size_t)r * 3 + c]);
    else if (c < 259) v = f2[(size_t)r * 256 + (c - 3)];
    else              v = 0;
    Xg[u] = v;
}

// ---------------- bf16 MFMA GEMM: C = relu(X[MxK] * W[NxK]^T + bias) -------------------
template <int BN, bool POOL>
__global__ __launch_bounds__(256) void mfma_gemm(const unsigned short* __restrict__ X,
                                                 const unsigned short* __restrict__ W,
                                                 const float* __restrict__ bias,
                                                 unsigned short* __restrict__ C,
                                                 int M, int N, int K) {
    constexpr int BM = 128, BK = 64;
    constexpr int AP = BK + 8;
    constexpr int NT = BN / 16;
    __shared__ __align__(16) unsigned short As[BM * AP];
    __shared__ __align__(16) unsigned short Bs[BN * AP];
    const int t = threadIdx.x;
    const int lane = t & 63, w = t >> 6;
    const int m0 = blockIdx.x * BM;
    const int n0 = blockIdx.y * BN;
    const int r16 = lane & 15, q = lane >> 4;

    f32x4 acc[2][NT];
#pragma unroll
    for (int i = 0; i < 2; ++i)
#pragma unroll
        for (int j = 0; j < NT; ++j) acc[i][j] = (f32x4){0.f, 0.f, 0.f, 0.f};

    for (int k0 = 0; k0 < K; k0 += BK) {
        for (int c = t; c < BM * (BK / 8); c += 256) {
            int row = c >> 3, ch = c & 7;
            *(short8*)&As[row * AP + ch * 8] =
                *(const short8*)&X[(size_t)(m0 + row) * K + k0 + ch * 8];
        }
        for (int c = t; c < BN * (BK / 8); c += 256) {
            int row = c >> 3, ch = c & 7;
            *(short8*)&Bs[row * AP + ch * 8] =
                *(const short8*)&W[(size_t)(n0 + row) * K + k0 + ch * 8];
        }
        __syncthreads();
#pragma unroll
        for (int kk = 0; kk < BK; kk += 32) {
            short8 a0 = *(const short8*)&As[(w * 32 + r16) * AP + kk + q * 8];
            short8 a1 = *(const short8*)&As[(w * 32 + 16 + r16) * AP + kk + q * 8];
#pragma unroll
            for (int j = 0; j < NT; ++j) {
                short8 bf = *(const short8*)&Bs[(j * 16 + r16) * AP + kk + q * 8];
                acc[0][j] = __builtin_amdgcn_mfma_f32_16x16x32_bf16(a0, bf, acc[0][j], 0, 0, 0);
                acc[1][j] = __builtin_amdgcn_mfma_f32_16x16x32_bf16(a1, bf, acc[1][j], 0, 0, 0);
            }
        }
        __syncthreads();
    }

    if (!POOL) {
#pragma unroll
        for (int i = 0; i < 2; ++i)
#pragma unroll
            for (int j = 0; j < NT; ++j) {
                int col = n0 + j * 16 + r16;
                float bv = bias[col];
#pragma unroll
                for (int r = 0; r < 4; ++r) {
                    int row = m0 + w * 32 + i * 16 + q * 4 + r;
                    C[(size_t)row * N + col] = f2bf(fmaxf(acc[i][j][r] + bv, 0.f));
                }
            }
    } else {
#pragma unroll
        for (int j = 0; j < NT; ++j) {
            int col = n0 + j * 16 + r16;
            float bv = bias[col];
            float mv = 0.f;
#pragma unroll
            for (int i = 0; i < 2; ++i)
#pragma unroll
                for (int r = 0; r < 4; ++r)
                    mv = fmaxf(mv, acc[i][j][r] + bv);
            mv = fmaxf(mv, __shfl_xor(mv, 16));
            mv = fmaxf(mv, __shfl_xor(mv, 32));
            if (q == 0)
                C[(size_t)((m0 >> 5) + w) * N + col] = f2bf(mv);
        }
    }
}

// ---------------- Final max over the 128 points (bf16 in, fp32 out) ----------------
__global__ __launch_bounds__(256) void maxn_kernel(const unsigned short* __restrict__ h,
                                                   float* __restrict__ out) {
    int id = blockIdx.x * 256 + threadIdx.x;  // 32*1024
    int o = id & 1023, b = id >> 10;
    const unsigned short* p = h + (size_t)b * 128 * 1024 + o;
    float m = 0.f;
    for (int n = 0; n < 128; ++n) m = fmaxf(m, bf2f(p[(size_t)n * 1024]));
    out[id] = m;
}

extern "C" void kernel_launch(void* const* d_in, const int* in_sizes, int n_in,
                              void* d_out, int out_size, void* d_ws, size_t ws_size,
                              hipStream_t stream) {
    const float* data = (const float*)d_in[0];
    const float* w10 = (const float*)d_in[1];  const float* b10 = (const float*)d_in[2];
    const float* w11 = (const float*)d_in[3];  const float* b11 = (const float*)d_in[4];
    const float* w12 = (const float*)d_in[5];  const float* b12 = (const float*)d_in[6];
    const float* w20 = (const float*)d_in[7];  const float* b20 = (const float*)d_in[8];
    const float* w21 = (const float*)d_in[9];  const float* b21 = (const float*)d_in[10];
    const float* w22 = (const float*)d_in[11]; const float* b22 = (const float*)d_in[12];
    const float* w30 = (const float*)d_in[13]; const float* b30 = (const float*)d_in[14];
    const float* w31 = (const float*)d_in[15]; const float* b31 = (const float*)d_in[16];
    const float* w32 = (const float*)d_in[17]; const float* b32 = (const float*)d_in[18];
    float* out = (float*)d_out;

    char* ws = (char*)d_ws;
    size_t off = 0;
    auto alloc = [&](size_t bytes) -> void* {
        void* p = ws + off;
        off += (bytes + 255) & ~(size_t)255;
        return p;
    };
    float* nxz1 = (float*)alloc((size_t)BT * S1 * 3 * 4);
    float* nxz2 = (float*)alloc((size_t)BT * S2 * 3 * 4);
    unsigned short* wb  = (unsigned short*)alloc((size_t)823296 * 2);
    unsigned short* f1  = (unsigned short*)alloc((size_t)8192 * 128 * 2);
    unsigned short* f2  = (unsigned short*)alloc((size_t)4096 * 256 * 2);
    unsigned short* xg3 = (unsigned short*)alloc((size_t)4096 * 320 * 2);
    unsigned short* C1  = (unsigned short*)alloc((size_t)4096 * 256 * 2);
    unsigned short* C2  = (unsigned short*)alloc((size_t)4096 * 512 * 2);
    unsigned short* C3  = (unsigned short*)alloc((size_t)4096 * 1024 * 2);

    const unsigned short* w11b = wb + 0;
    const unsigned short* w12b = wb + 4096;
    const unsigned short* w20p = wb + 12288;
    const unsigned short* w21b = wb + 36864;
    const unsigned short* w22b = wb + 53248;
    const unsigned short* w30b = wb + 86016;
    const unsigned short* w31b = wb + 167936;
    const unsigned short* w32b = wb + 299008;

    wconv_kernel<<<(823296 + 255) / 256, 256, 0, stream>>>(w11, w12, w20, w21, w22, w30, w31, w32, wb);

    // ---- module 1 ----
    fps1_kernel<<<BT, 256, 0, stream>>>(data, nxz1);
    m1_kernel<<<262144 / 128, 256, 0, stream>>>(data, nxz1, w10, b10, w11b, b11, w12b, b12, f1);
    // ---- module 2 ----
    fps2_kernel<<<BT, 64, 0, stream>>>(nxz1, nxz2);
    m2_kernel<<<131072 / 128, 256, 0, stream>>>(nxz1, nxz2, f1, w20p, b20, w21b, b21, w22b, b22, f2);
    // ---- module 3 ----
    gather3_kernel<<<(4096 * 320) / 256, 256, 0, stream>>>(nxz2, f2, xg3);
    mfma_gemm<128, false><<<dim3(4096 / 128, 2), 256, 0, stream>>>(xg3, w30b, b30, C1, 4096, 256, 320);
    mfma_gemm<128, false><<<dim3(4096 / 128, 4), 256, 0, stream>>>(C1, w31b, b31, C2, 4096, 512, 256);
    mfma_gemm<128, false><<<dim3(4096 / 128, 8), 256, 0, stream>>>(C2, w32b, b32, C3, 4096, 1024, 512);
    maxn_kernel<<<(BT * 1024) / 256, 256, 0, stream>>>(C3, out);
}

// Round 9
// 515.384 us; speedup vs baseline: 1.1181x; 1.1181x over previous
//
#include <hip/hip_runtime.h>
#include <hip/hip_bf16.h>
#include <cstdint>
#include <cstddef>

// Problem constants: data (4,8,4096,3) -> 32 batches x 4096 points
#define BT 32
#define N1 4096
#define S1 256
#define S2 128
#define KNB 32

typedef __attribute__((ext_vector_type(8))) short short8;   // 8 bf16 in 4 VGPRs
typedef __attribute__((ext_vector_type(4))) float f32x4;

__device__ __forceinline__ float sqdist(float ax, float ay, float az,
                                        float bx, float by, float bz) {
    // exact replication of sum((a-b)**2, axis=-1): mul then left-to-right add, NO fma
    float dx = __fsub_rn(ax, bx), dy = __fsub_rn(ay, by), dz = __fsub_rn(az, bz);
    return __fadd_rn(__fadd_rn(__fmul_rn(dx, dx), __fmul_rn(dy, dy)), __fmul_rn(dz, dz));
}

// bf16 round-to-nearest-even (values here are finite)
__device__ __forceinline__ unsigned short f2bf(float f) {
    unsigned u = __float_as_uint(f);
    return (unsigned short)((u + 0x7FFFu + ((u >> 16) & 1u)) >> 16);
}
__device__ __forceinline__ float bf2f(unsigned short h) {
    return __uint_as_float(((unsigned)h) << 16);
}

// pack (value, index) for argmax-with-first-index-tie-break: distances >= 0 so float
// bits are monotonic as uint; on equal value, larger ~idx == smaller idx wins.
__device__ __forceinline__ unsigned long long packvi(float v, int idx) {
    return ((unsigned long long)__float_as_uint(v) << 32) | (unsigned)(~idx);
}

// DPP row-rotate max for u64 (rotate within 16-lane rows; commutative reduce)
template <int CTRL>
__device__ __forceinline__ unsigned long long dppmax(unsigned long long v) {
    int lo = (int)(unsigned)(v & 0xFFFFFFFFull);
    int hi = (int)(unsigned)(v >> 32);
    int lo2 = __builtin_amdgcn_update_dpp(0, lo, CTRL, 0xF, 0xF, false);
    int hi2 = __builtin_amdgcn_update_dpp(0, hi, CTRL, 0xF, 0xF, false);
    unsigned long long o = ((unsigned long long)(unsigned)hi2 << 32) | (unsigned)lo2;
    return o > v ? o : v;
}
#define ROR1 0x121
#define ROR2 0x122
#define ROR4 0x124
#define ROR8 0x128

// ---------------- FPS module 1: N=4096 -> 256, one block/batch, 256 threads ----------
__global__ __launch_bounds__(256) void fps1_kernel(const float* __restrict__ xyz,
                                                   float* __restrict__ nxz) {
    const int b = blockIdx.x, tid = threadIdx.x;
    const int lane = tid & 63, wv = tid >> 6;      // 4 waves
    const float* X = xyz + (size_t)b * (N1 * 3);
    __shared__ float4 s4[N1];                      // 64 KB
    __shared__ unsigned long long slots[2][16];
    __shared__ float hist[S1 * 3];
    float px[16], py[16], pz[16], md[16];
    int bidx[16];
#pragma unroll
    for (int j = 0; j < 16; ++j) {
        int i = tid + 256 * j;
        float x = X[i * 3 + 0], y = X[i * 3 + 1], z = X[i * 3 + 2];
        s4[i] = make_float4(x, y, z, 0.f);
        px[j] = x; py[j] = y; pz[j] = z;
        md[j] = 1e10f;
        bidx[j] = i;
    }
    if (tid == 0) { hist[0] = X[0]; hist[1] = X[1]; hist[2] = X[2]; }
    __syncthreads();
    float4 c0 = s4[0];
    float lx = c0.x, ly = c0.y, lz = c0.z;
    for (int t = 1; t < S1; ++t) {
        float bv = -1.0f; int bi = 0;
#pragma unroll
        for (int j = 0; j < 16; ++j) {
            float d = sqdist(px[j], py[j], pz[j], lx, ly, lz);
            float m = fminf(md[j], d);
            md[j] = m;
            if (m > bv) { bv = m; bi = bidx[j]; }   // ascending flat idx: first max kept
        }
        unsigned long long best = packvi(bv, bi);
        best = dppmax<ROR1>(best);
        best = dppmax<ROR2>(best);
        best = dppmax<ROR4>(best);
        best = dppmax<ROR8>(best);                  // row (16-lane) max
        if ((lane & 15) == 0) slots[t & 1][wv * 4 + (lane >> 4)] = best;
        __syncthreads();
        unsigned long long w = slots[t & 1][lane & 15];
        w = dppmax<ROR1>(w);
        w = dppmax<ROR2>(w);
        w = dppmax<ROR4>(w);
        w = dppmax<ROR8>(w);
        int vi = (int)(~(unsigned)w);
        float4 c = s4[vi];
        lx = c.x; ly = c.y; lz = c.z;
        if (tid == 0) { hist[t * 3 + 0] = lx; hist[t * 3 + 1] = ly; hist[t * 3 + 2] = lz; }
    }
    __syncthreads();
    for (int u = tid; u < S1 * 3; u += 256) nxz[(size_t)b * S1 * 3 + u] = hist[u];
}

// ---------------- FPS module 2: N=256 -> 128, ONE WAVE per batch ----------
__global__ __launch_bounds__(64) void fps2_kernel(const float* __restrict__ xyz1,
                                                  float* __restrict__ nxz2) {
    const int b = blockIdx.x, lane = threadIdx.x;
    const float* X = xyz1 + (size_t)b * (S1 * 3);
    __shared__ float4 s4[S1];
    float px[4], py[4], pz[4], md[4];
    int bidx[4];
#pragma unroll
    for (int j = 0; j < 4; ++j) {
        int i = lane + 64 * j;
        float x = X[i * 3 + 0], y = X[i * 3 + 1], z = X[i * 3 + 2];
        s4[i] = make_float4(x, y, z, 0.f);
        px[j] = x; py[j] = y; pz[j] = z;
        md[j] = 1e10f;
        bidx[j] = i;
    }
    if (lane == 0) {
        nxz2[(size_t)b * S2 * 3 + 0] = X[0];
        nxz2[(size_t)b * S2 * 3 + 1] = X[1];
        nxz2[(size_t)b * S2 * 3 + 2] = X[2];
    }
    // single wave: LDS writes above are wave-synchronous
    float4 cc = s4[0];
    float lx = cc.x, ly = cc.y, lz = cc.z;
    for (int t = 1; t < S2; ++t) {
        float bv = -1.0f; int bi = 0;
#pragma unroll
        for (int j = 0; j < 4; ++j) {
            float d = sqdist(px[j], py[j], pz[j], lx, ly, lz);
            float m = fminf(md[j], d);
            md[j] = m;
            if (m > bv) { bv = m; bi = bidx[j]; }
        }
        unsigned long long best = packvi(bv, bi);
        best = dppmax<ROR1>(best);
        best = dppmax<ROR2>(best);
        best = dppmax<ROR4>(best);
        best = dppmax<ROR8>(best);
        { unsigned long long o = __shfl_xor(best, 16); best = o > best ? o : best; }
        { unsigned long long o = __shfl_xor(best, 32); best = o > best ? o : best; }
        int vi = (int)(~(unsigned)best);
        float4 c = s4[vi];
        lx = c.x; ly = c.y; lz = c.z;
        if (lane == 0) {
            float* dst = nxz2 + ((size_t)b * S2 + t) * 3;
            dst[0] = lx; dst[1] = ly; dst[2] = lz;
        }
    }
}

// ---------------- Ball query 1 (wave-per-center): 4096 pts, r=0.2 ----------
__global__ __launch_bounds__(256) void ballq1_kernel(const float* __restrict__ xyz,
                                                     const float* __restrict__ nxz,
                                                     int* __restrict__ gidx) {
    const int wid = (blockIdx.x * 256 + threadIdx.x) >> 6;
    const int lane = threadIdx.x & 63;
    const int b = wid >> 8;
    const float* X = xyz + (size_t)b * (N1 * 3);
    const float* C = nxz + (size_t)wid * 3;
    const float cx = C[0], cy = C[1], cz = C[2];
    const float r2 = (float)(0.2 * 0.2);
    int* G = gidx + (size_t)wid * KNB;
    int cnt = 0, first = 0;
    bool found = false;
    for (int j0 = 0; j0 < N1 && cnt < KNB; j0 += 64) {
        int j = j0 + lane;
        float d2 = sqdist(cx, cy, cz, X[j * 3 + 0], X[j * 3 + 1], X[j * 3 + 2]);
        bool hit = d2 < r2;
        unsigned long long mask = __ballot(hit);
        if (!found && mask) { first = j0 + __builtin_ctzll(mask); found = true; }
        if (hit) {
            int pos = cnt + __popcll(mask & ((1ull << lane) - 1ull));
            if (pos < KNB) G[pos] = j;
        }
        cnt += __popcll(mask);
    }
    if (cnt < KNB) {
        int pad = found ? first : 0;
        if (lane >= cnt && lane < KNB) G[lane] = pad;
    }
}

// ---------------- Ball query 2 (wave-per-center): 256 pts, r=0.4 ----------
__global__ __launch_bounds__(256) void ballq2_kernel(const float* __restrict__ xyz1,
                                                     const float* __restrict__ nxz2,
                                                     int* __restrict__ gidx) {
    const int wid = (blockIdx.x * 256 + threadIdx.x) >> 6;
    const int lane = threadIdx.x & 63;
    const int b = wid >> 7;
    const float* X = xyz1 + (size_t)b * (S1 * 3);
    const float* C = nxz2 + (size_t)wid * 3;
    const float cx = C[0], cy = C[1], cz = C[2];
    const float r2 = (float)(0.4 * 0.4);
    int* G = gidx + (size_t)wid * KNB;
    int cnt = 0, first = 0;
    bool found = false;
    for (int j0 = 0; j0 < S1 && cnt < KNB; j0 += 64) {
        int j = j0 + lane;
        float d2 = sqdist(cx, cy, cz, X[j * 3 + 0], X[j * 3 + 1], X[j * 3 + 2]);
        bool hit = d2 < r2;
        unsigned long long mask = __ballot(hit);
        if (!found && mask) { first = j0 + __builtin_ctzll(mask); found = true; }
        if (hit) {
            int pos = cnt + __popcll(mask & ((1ull << lane) - 1ull));
            if (pos < KNB) G[pos] = j;
        }
        cnt += __popcll(mask);
    }
    if (cnt < KNB) {
        int pad = found ? first : 0;
        if (lane >= cnt && lane < KNB) G[lane] = pad;
    }
}

// ---------------- Weight conversion: fp32 -> bf16 arena, K padded to x64 ----------------
//  w11b@0      64x64   | w12b@4096  128x64 | w20p@12288 128x192 (PERM: feat-first)
//  w21b@36864  128x128 | w22b@53248 256x128| w30p@86016 256x320 (PERM: feat-first)
//  w31b@167936 512x256 | w32b@299008 1024x512  total 823296
__global__ __launch_bounds__(256) void wconv_kernel(
    const float* __restrict__ w11, const float* __restrict__ w12,
    const float* __restrict__ w20, const float* __restrict__ w21,
    const float* __restrict__ w22, const float* __restrict__ w30,
    const float* __restrict__ w31, const float* __restrict__ w32,
    unsigned short* __restrict__ wb) {
    int u = blockIdx.x * 256 + threadIdx.x;
    if (u >= 823296) return;
    const float* src; int base, Kp, Ko; int perm = 0;   // perm: feature-count for feat-first layout
    if      (u < 4096)   { src = w11; base = 0;      Kp = 64;  Ko = 64;  }
    else if (u < 12288)  { src = w12; base = 4096;   Kp = 64;  Ko = 64;  }
    else if (u < 36864)  { src = w20; base = 12288;  Kp = 192; Ko = 131; perm = 128; }
    else if (u < 53248)  { src = w21; base = 36864;  Kp = 128; Ko = 128; }
    else if (u < 86016)  { src = w22; base = 53248;  Kp = 128; Ko = 128; }
    else if (u < 167936) { src = w30; base = 86016;  Kp = 320; Ko = 259; perm = 256; }
    else if (u < 299008) { src = w31; base = 167936; Kp = 256; Ko = 256; }
    else                 { src = w32; base = 299008; Kp = 512; Ko = 512; }
    int local = u - base;
    int n = local / Kp, k = local - n * Kp;
    float v;
    if (perm) {
        // feat-first: col k<perm -> src[.,k+3] (features), k in [perm,perm+3) -> src[.,k-perm] (xyz), else 0
        int ksrc = (k < perm) ? (k + 3) : ((k < perm + 3) ? (k - perm) : -1);
        v = (ksrc >= 0) ? src[(size_t)n * Ko + ksrc] : 0.f;
    } else {
        v = (k < Ko) ? src[(size_t)n * Ko + k] : 0.f;
    }
    wb[u] = f2bf(v);
}

// ---------------- Module 1 fused: gather + L0(K=3, VALU) + L1 + L2 MFMA + pool ---------
__global__ __launch_bounds__(256) void m1_kernel(
    const float* __restrict__ xyz, const float* __restrict__ nxz,
    const int* __restrict__ g1,
    const float* __restrict__ w10, const float* __restrict__ b10,
    const unsigned short* __restrict__ w11b, const float* __restrict__ b11,
    const unsigned short* __restrict__ w12b, const float* __restrict__ b12,
    unsigned short* __restrict__ f1) {
    constexpr int AP = 72;
    __shared__ __align__(16) unsigned short As[128 * AP];
    __shared__ __align__(16) unsigned short Hs[128 * AP];
    __shared__ __align__(16) unsigned short Bs[128 * AP];
    __shared__ float sxyz[128 * 3];
    const int t = threadIdx.x;
    const int lane = t & 63, w = t >> 6;
    const int r16 = lane & 15, q = lane >> 4;
    const int m0 = blockIdx.x * 128;

    if (t < 128) {
        int row = m0 + t, bs = row >> 5, b = bs >> 8, j = g1[row];
        const float* P = xyz + ((size_t)b * N1 + j) * 3;
        const float* Cc = nxz + (size_t)bs * 3;
        sxyz[t * 3 + 0] = P[0] - Cc[0];
        sxyz[t * 3 + 1] = P[1] - Cc[1];
        sxyz[t * 3 + 2] = P[2] - Cc[2];
    }
    for (int c = t; c < 64 * 8; c += 256) {
        int row = c >> 3, ch = c & 7;
        *(short8*)&Bs[row * AP + ch * 8] = *(const short8*)&w11b[row * 64 + ch * 8];
    }
    __syncthreads();
    {
        const int r = t >> 1, half = (t & 1) * 32;
        const float x = sxyz[r * 3 + 0], y = sxyz[r * 3 + 1], z = sxyz[r * 3 + 2];
        unsigned short tmp[32];
#pragma unroll
        for (int o = 0; o < 32; ++o) {
            int oo = half + o;
            float acc = b10[oo];
            acc = fmaf(x, w10[oo * 3 + 0], acc);
            acc = fmaf(y, w10[oo * 3 + 1], acc);
            acc = fmaf(z, w10[oo * 3 + 2], acc);
            tmp[o] = f2bf(fmaxf(acc, 0.f));
        }
#pragma unroll
        for (int c2 = 0; c2 < 4; ++c2)
            *(short8*)&As[r * AP + half + c2 * 8] = *(short8*)&tmp[c2 * 8];
    }
    __syncthreads();
    {
        f32x4 acc[2][4];
#pragma unroll
        for (int i = 0; i < 2; ++i)
#pragma unroll
            for (int j = 0; j < 4; ++j) acc[i][j] = (f32x4){0.f, 0.f, 0.f, 0.f};
#pragma unroll
        for (int kk = 0; kk < 64; kk += 32) {
            short8 a0 = *(const short8*)&As[(w * 32 + r16) * AP + kk + q * 8];
            short8 a1 = *(const short8*)&As[(w * 32 + 16 + r16) * AP + kk + q * 8];
#pragma unroll
            for (int j = 0; j < 4; ++j) {
                short8 bf = *(const short8*)&Bs[(j * 16 + r16) * AP + kk + q * 8];
                acc[0][j] = __builtin_amdgcn_mfma_f32_16x16x32_bf16(a0, bf, acc[0][j], 0, 0, 0);
                acc[1][j] = __builtin_amdgcn_mfma_f32_16x16x32_bf16(a1, bf, acc[1][j], 0, 0, 0);
            }
        }
#pragma unroll
        for (int i = 0; i < 2; ++i)
#pragma unroll
            for (int j = 0; j < 4; ++j) {
                int col = j * 16 + r16;
                float bv = b11[col];
#pragma unroll
                for (int r = 0; r < 4; ++r) {
                    int row = w * 32 + i * 16 + q * 4 + r;
                    Hs[row * AP + col] = f2bf(fmaxf(acc[i][j][r] + bv, 0.f));
                }
            }
    }
    __syncthreads();
    for (int c = t; c < 128 * 8; c += 256) {
        int row = c >> 3, ch = c & 7;
        *(short8*)&Bs[row * AP + ch * 8] = *(const short8*)&w12b[row * 64 + ch * 8];
    }
    __syncthreads();
    {
        f32x4 acc[2][8];
#pragma unroll
        for (int i = 0; i < 2; ++i)
#pragma unroll
            for (int j = 0; j < 8; ++j) acc[i][j] = (f32x4){0.f, 0.f, 0.f, 0.f};
#pragma unroll
        for (int kk = 0; kk < 64; kk += 32) {
            short8 a0 = *(const short8*)&Hs[(w * 32 + r16) * AP + kk + q * 8];
            short8 a1 = *(const short8*)&Hs[(w * 32 + 16 + r16) * AP + kk + q * 8];
#pragma unroll
            for (int j = 0; j < 8; ++j) {
                short8 bf = *(const short8*)&Bs[(j * 16 + r16) * AP + kk + q * 8];
                acc[0][j] = __builtin_amdgcn_mfma_f32_16x16x32_bf16(a0, bf, acc[0][j], 0, 0, 0);
                acc[1][j] = __builtin_amdgcn_mfma_f32_16x16x32_bf16(a1, bf, acc[1][j], 0, 0, 0);
            }
        }
#pragma unroll
        for (int j = 0; j < 8; ++j) {
            int col = j * 16 + r16;
            float bv = b12[col];
            float mv = 0.f;
#pragma unroll
            for (int i = 0; i < 2; ++i)
#pragma unroll
                for (int r = 0; r < 4; ++r)
                    mv = fmaxf(mv, acc[i][j][r] + bv);
            mv = fmaxf(mv, __shfl_xor(mv, 16));
            mv = fmaxf(mv, __shfl_xor(mv, 32));
            if (q == 0)
                f1[(size_t)((m0 >> 5) + w) * 128 + col] = f2bf(mv);
        }
    }
}

// ---------------- Module 2 fully fused: gather + L0(192) + L1(128) + L2(256)+pool ----
__global__ __launch_bounds__(256) void m2_kernel(
    const float* __restrict__ xyz1, const float* __restrict__ nxz2,
    const int* __restrict__ g2, const unsigned short* __restrict__ f1,
    const unsigned short* __restrict__ w20p, const float* __restrict__ b20,
    const unsigned short* __restrict__ w21b, const float* __restrict__ b21,
    const unsigned short* __restrict__ w22b, const float* __restrict__ b22,
    unsigned short* __restrict__ f2) {
    constexpr int AP = 72, HP = 136;
    __shared__ __align__(16) unsigned short smem[36864];   // 72 KB
    unsigned short* R1 = smem;
    unsigned short* R2 = smem + 18432;
    unsigned short* As = R1;
    unsigned short* Bs = R1 + 9216;
    unsigned short* H1 = R2;
    unsigned short* H2 = R1;
    unsigned short* Bs2 = R2;
    __shared__ int ribase[128];
    __shared__ unsigned short sxb[128 * 3];
    const int t = threadIdx.x;
    const int lane = t & 63, w = t >> 6;
    const int r16 = lane & 15, q = lane >> 4;
    const int m0 = blockIdx.x * 128;

    if (t < 128) {
        int row = m0 + t, bs = row >> 5, b = bs >> 7, j = g2[row];
        ribase[t] = (b * 256 + j) * 128;
        const float* P = xyz1 + ((size_t)b * S1 + j) * 3;
        const float* Cc = nxz2 + (size_t)bs * 3;
        sxb[t * 3 + 0] = f2bf(P[0] - Cc[0]);
        sxb[t * 3 + 1] = f2bf(P[1] - Cc[1]);
        sxb[t * 3 + 2] = f2bf(P[2] - Cc[2]);
    }
    __syncthreads();

    // ---- L0: K=192 (3 tiles), N=128 ----
    f32x4 acc[2][8];
#pragma unroll
    for (int i = 0; i < 2; ++i)
#pragma unroll
        for (int j = 0; j < 8; ++j) acc[i][j] = (f32x4){0.f, 0.f, 0.f, 0.f};
    for (int kt = 0; kt < 3; ++kt) {
        const int k0 = kt * 64;
        if (kt < 2) {
            for (int c = t; c < 128 * 8; c += 256) {
                int row = c >> 3, ch = c & 7;
                *(short8*)&As[row * AP + ch * 8] =
                    *(const short8*)&f1[(size_t)ribase[row] + k0 + ch * 8];
            }
        } else {
            for (int c = t; c < 128 * 8; c += 256) {
                int row = c >> 3, ch = c & 7;
                short8 v = (short8){0, 0, 0, 0, 0, 0, 0, 0};
                if (ch == 0) {
                    v[0] = (short)sxb[row * 3 + 0];
                    v[1] = (short)sxb[row * 3 + 1];
                    v[2] = (short)sxb[row * 3 + 2];
                }
                *(short8*)&As[row * AP + ch * 8] = v;
            }
        }
        for (int c = t; c < 128 * 8; c += 256) {
            int row = c >> 3, ch = c & 7;
            *(short8*)&Bs[row * AP + ch * 8] =
                *(const short8*)&w20p[(size_t)row * 192 + k0 + ch * 8];
        }
        __syncthreads();
#pragma unroll
        for (int kk = 0; kk < 64; kk += 32) {
            short8 a0 = *(const short8*)&As[(w * 32 + r16) * AP + kk + q * 8];
            short8 a1 = *(const short8*)&As[(w * 32 + 16 + r16) * AP + kk + q * 8];
#pragma unroll
            for (int j = 0; j < 8; ++j) {
                short8 bf = *(const short8*)&Bs[(j * 16 + r16) * AP + kk + q * 8];
                acc[0][j] = __builtin_amdgcn_mfma_f32_16x16x32_bf16(a0, bf, acc[0][j], 0, 0, 0);
                acc[1][j] = __builtin_amdgcn_mfma_f32_16x16x32_bf16(a1, bf, acc[1][j], 0, 0, 0);
            }
        }
        __syncthreads();
    }
#pragma unroll
    for (int i = 0; i < 2; ++i)
#pragma unroll
        for (int j = 0; j < 8; ++j) {
            int col = j * 16 + r16;
            float bv = b20[col];
#pragma unroll
            for (int r = 0; r < 4; ++r) {
                int row = w * 32 + i * 16 + q * 4 + r;
                H1[row * HP + col] = f2bf(fmaxf(acc[i][j][r] + bv, 0.f));
            }
        }
    __syncthreads();

    // ---- L1: K=128 (2 tiles), N=128 ----
#pragma unroll
    for (int i = 0; i < 2; ++i)
#pragma unroll
        for (int j = 0; j < 8; ++j) acc[i][j] = (f32x4){0.f, 0.f, 0.f, 0.f};
    for (int kt = 0; kt < 2; ++kt) {
        const int k0 = kt * 64;
        for (int c = t; c < 128 * 8; c += 256) {
            int row = c >> 3, ch = c & 7;
            *(short8*)&As[row * AP + ch * 8] =
                *(const short8*)&w21b[(size_t)row * 128 + k0 + ch * 8];
        }
        __syncthreads();
#pragma unroll
        for (int kk = 0; kk < 64; kk += 32) {
            short8 a0 = *(const short8*)&H1[(w * 32 + r16) * HP + k0 + kk + q * 8];
            short8 a1 = *(const short8*)&H1[(w * 32 + 16 + r16) * HP + k0 + kk + q * 8];
#pragma unroll
            for (int j = 0; j < 8; ++j) {
                short8 bf = *(const short8*)&As[(j * 16 + r16) * AP + kk + q * 8];
                acc[0][j] = __builtin_amdgcn_mfma_f32_16x16x32_bf16(a0, bf, acc[0][j], 0, 0, 0);
                acc[1][j] = __builtin_amdgcn_mfma_f32_16x16x32_bf16(a1, bf, acc[1][j], 0, 0, 0);
            }
        }
        __syncthreads();
    }
#pragma unroll
    for (int i = 0; i < 2; ++i)
#pragma unroll
        for (int j = 0; j < 8; ++j) {
            int col = j * 16 + r16;
            float bv = b21[col];
#pragma unroll
            for (int r = 0; r < 4; ++r) {
                int row = w * 32 + i * 16 + q * 4 + r;
                H2[row * HP + col] = f2bf(fmaxf(acc[i][j][r] + bv, 0.f));
            }
        }
    __syncthreads();

    // ---- L2: K=128 (2 tiles), N=256 + pool ----
    f32x4 acc2[2][16];
#pragma unroll
    for (int i = 0; i < 2; ++i)
#pragma unroll
        for (int j = 0; j < 16; ++j) acc2[i][j] = (f32x4){0.f, 0.f, 0.f, 0.f};
    for (int kt = 0; kt < 2; ++kt) {
        const int k0 = kt * 64;
        for (int c = t; c < 256 * 8; c += 256) {
            int row = c >> 3, ch = c & 7;
            *(short8*)&Bs2[row * AP + ch * 8] =
                *(const short8*)&w22b[(size_t)row * 128 + k0 + ch * 8];
        }
        __syncthreads();
#pragma unroll
        for (int kk = 0; kk < 64; kk += 32) {
            short8 a0 = *(const short8*)&H2[(w * 32 + r16) * HP + k0 + kk + q * 8];
            short8 a1 = *(const short8*)&H2[(w * 32 + 16 + r16) * HP + k0 + kk + q * 8];
#pragma unroll
            for (int j = 0; j < 16; ++j) {
                short8 bf = *(const short8*)&Bs2[(j * 16 + r16) * AP + kk + q * 8];
                acc2[0][j] = __builtin_amdgcn_mfma_f32_16x16x32_bf16(a0, bf, acc2[0][j], 0, 0, 0);
                acc2[1][j] = __builtin_amdgcn_mfma_f32_16x16x32_bf16(a1, bf, acc2[1][j], 0, 0, 0);
            }
        }
        __syncthreads();
    }
#pragma unroll
    for (int j = 0; j < 16; ++j) {
        int col = j * 16 + r16;
        float bv = b22[col];
        float mv = 0.f;
#pragma unroll
        for (int i = 0; i < 2; ++i)
#pragma unroll
            for (int r = 0; r < 4; ++r)
                mv = fmaxf(mv, acc2[i][j][r] + bv);
        mv = fmaxf(mv, __shfl_xor(mv, 16));
        mv = fmaxf(mv, __shfl_xor(mv, 32));
        if (q == 0)
            f2[(size_t)((m0 >> 5) + w) * 256 + col] = f2bf(mv);
    }
}

// ---------------- Module 3 layer 0 with fused concat (feat-first K=320) ---------------
// A row r: cols[0..255] = f2[r][:], cols[256..258] = nxz2[r] (raw), rest 0.
__global__ __launch_bounds__(256) void l30_kernel(
    const float* __restrict__ nxz2, const unsigned short* __restrict__ f2,
    const unsigned short* __restrict__ w30p, const float* __restrict__ bias,
    unsigned short* __restrict__ C) {
    constexpr int AP = 72;
    __shared__ __align__(16) unsigned short As[128 * AP];
    __shared__ __align__(16) unsigned short Bs[128 * AP];
    const int t = threadIdx.x;
    const int lane = t & 63, w = t >> 6;
    const int r16 = lane & 15, q = lane >> 4;
    const int m0 = blockIdx.x * 128;
    const int n0 = blockIdx.y * 128;

    f32x4 acc[2][8];
#pragma unroll
    for (int i = 0; i < 2; ++i)
#pragma unroll
        for (int j = 0; j < 8; ++j) acc[i][j] = (f32x4){0.f, 0.f, 0.f, 0.f};

    for (int kt = 0; kt < 5; ++kt) {
        const int k0 = kt * 64;
        if (kt < 4) {
            for (int c = t; c < 128 * 8; c += 256) {
                int row = c >> 3, ch = c & 7;
                *(short8*)&As[row * AP + ch * 8] =
                    *(const short8*)&f2[(size_t)(m0 + row) * 256 + k0 + ch * 8];
            }
        } else {
            for (int c = t; c < 128 * 8; c += 256) {
                int row = c >> 3, ch = c & 7;
                short8 v = (short8){0, 0, 0, 0, 0, 0, 0, 0};
                if (ch == 0) {
                    const float* P = nxz2 + (size_t)(m0 + row) * 3;
                    v[0] = (short)f2bf(P[0]);
                    v[1] = (short)f2bf(P[1]);
                    v[2] = (short)f2bf(P[2]);
                }
                *(short8*)&As[row * AP + ch * 8] = v;
            }
        }
        for (int c = t; c < 128 * 8; c += 256) {
            int row = c >> 3, ch = c & 7;
            *(short8*)&Bs[row * AP + ch * 8] =
                *(const short8*)&w30p[(size_t)(n0 + row) * 320 + k0 + ch * 8];
        }
        __syncthreads();
#pragma unroll
        for (int kk = 0; kk < 64; kk += 32) {
            short8 a0 = *(const short8*)&As[(w * 32 + r16) * AP + kk + q * 8];
            short8 a1 = *(const short8*)&As[(w * 32 + 16 + r16) * AP + kk + q * 8];
#pragma unroll
            for (int j = 0; j < 8; ++j) {
                short8 bf = *(const short8*)&Bs[(j * 16 + r16) * AP + kk + q * 8];
                acc[0][j] = __builtin_amdgcn_mfma_f32_16x16x32_bf16(a0, bf, acc[0][j], 0, 0, 0);
                acc[1][j] = __builtin_amdgcn_mfma_f32_16x16x32_bf16(a1, bf, acc[1][j], 0, 0, 0);
            }
        }
        __syncthreads();
    }
#pragma unroll
    for (int i = 0; i < 2; ++i)
#pragma unroll
        for (int j = 0; j < 8; ++j) {
            int col = n0 + j * 16 + r16;
            float bv = bias[col];
#pragma unroll
            for (int r = 0; r < 4; ++r) {
                int row = m0 + w * 32 + i * 16 + q * 4 + r;
                C[(size_t)row * 256 + col] = f2bf(fmaxf(acc[i][j][r] + bv, 0.f));
            }
        }
}

// ---------------- bf16 MFMA GEMM: C = relu(X[MxK] * W[NxK]^T + bias) -------------------
template <int BN, bool POOL>
__global__ __launch_bounds__(256) void mfma_gemm(const unsigned short* __restrict__ X,
                                                 const unsigned short* __restrict__ W,
                                                 const float* __restrict__ bias,
                                                 unsigned short* __restrict__ C,
                                                 int M, int N, int K) {
    constexpr int BM = 128, BK = 64;
    constexpr int AP = BK + 8;
    constexpr int NT = BN / 16;
    __shared__ __align__(16) unsigned short As[BM * AP];
    __shared__ __align__(16) unsigned short Bs[BN * AP];
    const int t = threadIdx.x;
    const int lane = t & 63, w = t >> 6;
    const int m0 = blockIdx.x * BM;
    const int n0 = blockIdx.y * BN;
    const int r16 = lane & 15, q = lane >> 4;

    f32x4 acc[2][NT];
#pragma unroll
    for (int i = 0; i < 2; ++i)
#pragma unroll
        for (int j = 0; j < NT; ++j) acc[i][j] = (f32x4){0.f, 0.f, 0.f, 0.f};

    for (int k0 = 0; k0 < K; k0 += BK) {
        for (int c = t; c < BM * (BK / 8); c += 256) {
            int row = c >> 3, ch = c & 7;
            *(short8*)&As[row * AP + ch * 8] =
                *(const short8*)&X[(size_t)(m0 + row) * K + k0 + ch * 8];
        }
        for (int c = t; c < BN * (BK / 8); c += 256) {
            int row = c >> 3, ch = c & 7;
            *(short8*)&Bs[row * AP + ch * 8] =
                *(const short8*)&W[(size_t)(n0 + row) * K + k0 + ch * 8];
        }
        __syncthreads();
#pragma unroll
        for (int kk = 0; kk < BK; kk += 32) {
            short8 a0 = *(const short8*)&As[(w * 32 + r16) * AP + kk + q * 8];
            short8 a1 = *(const short8*)&As[(w * 32 + 16 + r16) * AP + kk + q * 8];
#pragma unroll
            for (int j = 0; j < NT; ++j) {
                short8 bf = *(const short8*)&Bs[(j * 16 + r16) * AP + kk + q * 8];
                acc[0][j] = __builtin_amdgcn_mfma_f32_16x16x32_bf16(a0, bf, acc[0][j], 0, 0, 0);
                acc[1][j] = __builtin_amdgcn_mfma_f32_16x16x32_bf16(a1, bf, acc[1][j], 0, 0, 0);
            }
        }
        __syncthreads();
    }

    if (!POOL) {
#pragma unroll
        for (int i = 0; i < 2; ++i)
#pragma unroll
            for (int j = 0; j < NT; ++j) {
                int col = n0 + j * 16 + r16;
                float bv = bias[col];
#pragma unroll
                for (int r = 0; r < 4; ++r) {
                    int row = m0 + w * 32 + i * 16 + q * 4 + r;
                    C[(size_t)row * N + col] = f2bf(fmaxf(acc[i][j][r] + bv, 0.f));
                }
            }
    } else {
#pragma unroll
        for (int j = 0; j < NT; ++j) {
            int col = n0 + j * 16 + r16;
            float bv = bias[col];
            float mv = 0.f;
#pragma unroll
            for (int i = 0; i < 2; ++i)
#pragma unroll
                for (int r = 0; r < 4; ++r)
                    mv = fmaxf(mv, acc[i][j][r] + bv);
            mv = fmaxf(mv, __shfl_xor(mv, 16));
            mv = fmaxf(mv, __shfl_xor(mv, 32));
            if (q == 0)
                C[(size_t)((m0 >> 5) + w) * N + col] = f2bf(mv);
        }
    }
}

// ---------------- Final max over the 128 points (bf16 in, fp32 out) ----------------
__global__ __launch_bounds__(256) void maxn_kernel(const unsigned short* __restrict__ h,
                                                   float* __restrict__ out) {
    int id = blockIdx.x * 256 + threadIdx.x;  // 32*1024
    int o = id & 1023, b = id >> 10;
    const unsigned short* p = h + (size_t)b * 128 * 1024 + o;
    float m = 0.f;
    for (int n = 0; n < 128; ++n) m = fmaxf(m, bf2f(p[(size_t)n * 1024]));
    out[id] = m;
}

extern "C" void kernel_launch(void* const* d_in, const int* in_sizes, int n_in,
                              void* d_out, int out_size, void* d_ws, size_t ws_size,
                              hipStream_t stream) {
    const float* data = (const float*)d_in[0];
    const float* w10 = (const float*)d_in[1];  const float* b10 = (const float*)d_in[2];
    const float* w11 = (const float*)d_in[3];  const float* b11 = (const float*)d_in[4];
    const float* w12 = (const float*)d_in[5];  const float* b12 = (const float*)d_in[6];
    const float* w20 = (const float*)d_in[7];  const float* b20 = (const float*)d_in[8];
    const float* w21 = (const float*)d_in[9];  const float* b21 = (const float*)d_in[10];
    const float* w22 = (const float*)d_in[11]; const float* b22 = (const float*)d_in[12];
    const float* w30 = (const float*)d_in[13]; const float* b30 = (const float*)d_in[14];
    const float* w31 = (const float*)d_in[15]; const float* b31 = (const float*)d_in[16];
    const float* w32 = (const float*)d_in[17]; const float* b32 = (const float*)d_in[18];
    float* out = (float*)d_out;

    char* ws = (char*)d_ws;
    size_t off = 0;
    auto alloc = [&](size_t bytes) -> void* {
        void* p = ws + off;
        off += (bytes + 255) & ~(size_t)255;
        return p;
    };
    float* nxz1 = (float*)alloc((size_t)BT * S1 * 3 * 4);
    int*   g1   = (int*)  alloc((size_t)BT * S1 * KNB * 4);
    float* nxz2 = (float*)alloc((size_t)BT * S2 * 3 * 4);
    int*   g2   = (int*)  alloc((size_t)BT * S2 * KNB * 4);
    unsigned short* wb  = (unsigned short*)alloc((size_t)823296 * 2);
    unsigned short* f1  = (unsigned short*)alloc((size_t)8192 * 128 * 2);
    unsigned short* f2  = (unsigned short*)alloc((size_t)4096 * 256 * 2);
    unsigned short* C1  = (unsigned short*)alloc((size_t)4096 * 256 * 2);
    unsigned short* C2  = (unsigned short*)alloc((size_t)4096 * 512 * 2);
    unsigned short* C3  = (unsigned short*)alloc((size_t)4096 * 1024 * 2);

    const unsigned short* w11b = wb + 0;
    const unsigned short* w12b = wb + 4096;
    const unsigned short* w20p = wb + 12288;
    const unsigned short* w21b = wb + 36864;
    const unsigned short* w22b = wb + 53248;
    const unsigned short* w30p = wb + 86016;
    const unsigned short* w31b = wb + 167936;
    const unsigned short* w32b = wb + 299008;

    wconv_kernel<<<(823296 + 255) / 256, 256, 0, stream>>>(w11, w12, w20, w21, w22, w30, w31, w32, wb);

    // ---- module 1 ----
    fps1_kernel<<<BT, 256, 0, stream>>>(data, nxz1);
    ballq1_kernel<<<(BT * S1) / 4, 256, 0, stream>>>(data, nxz1, g1);
    m1_kernel<<<262144 / 128, 256, 0, stream>>>(data, nxz1, g1, w10, b10, w11b, b11, w12b, b12, f1);
    // ---- module 2 ----
    fps2_kernel<<<BT, 64, 0, stream>>>(nxz1, nxz2);
    ballq2_kernel<<<(BT * S2) / 4, 256, 0, stream>>>(nxz1, nxz2, g2);
    m2_kernel<<<131072 / 128, 256, 0, stream>>>(nxz1, nxz2, g2, f1, w20p, b20, w21b, b21, w22b, b22, f2);
    // ---- module 3 ----
    l30_kernel<<<dim3(4096 / 128, 2), 256, 0, stream>>>(nxz2, f2, w30p, b30, C1);
    mfma_gemm<128, false><<<dim3(4096 / 128, 4), 256, 0, stream>>>(C1, w31b, b31, C2, 4096, 512, 256);
    mfma_gemm<128, false><<<dim3(4096 / 128, 8), 256, 0, stream>>>(C2, w32b, b32, C3, 4096, 1024, 512);
    maxn_kernel<<<(BT * 1024) / 256, 256, 0, stream>>>(C3, out);
}

// Round 10
// 512.930 us; speedup vs baseline: 1.1234x; 1.0048x over previous
//
#include <hip/hip_runtime.h>
#include <hip/hip_bf16.h>
#include <cstdint>
#include <cstddef>

// Problem constants: data (4,8,4096,3) -> 32 batches x 4096 points
#define BT 32
#define N1 4096
#define S1 256
#define S2 128
#define KNB 32

typedef __attribute__((ext_vector_type(8))) short short8;   // 8 bf16 in 4 VGPRs
typedef __attribute__((ext_vector_type(4))) float f32x4;

__device__ __forceinline__ float sqdist(float ax, float ay, float az,
                                        float bx, float by, float bz) {
    // exact replication of sum((a-b)**2, axis=-1): mul then left-to-right add, NO fma
    float dx = __fsub_rn(ax, bx), dy = __fsub_rn(ay, by), dz = __fsub_rn(az, bz);
    return __fadd_rn(__fadd_rn(__fmul_rn(dx, dx), __fmul_rn(dy, dy)), __fmul_rn(dz, dz));
}

// bf16 round-to-nearest-even (values here are finite)
__device__ __forceinline__ unsigned short f2bf(float f) {
    unsigned u = __float_as_uint(f);
    return (unsigned short)((u + 0x7FFFu + ((u >> 16) & 1u)) >> 16);
}
__device__ __forceinline__ float bf2f(unsigned short h) {
    return __uint_as_float(((unsigned)h) << 16);
}

// pack (value, index) for argmax-with-first-index-tie-break: distances >= 0 so float
// bits are monotonic as uint; on equal value, larger ~idx == smaller idx wins.
__device__ __forceinline__ unsigned long long packvi(float v, int idx) {
    return ((unsigned long long)__float_as_uint(v) << 32) | (unsigned)(~idx);
}

// DPP row-rotate max for u64 (rotate within 16-lane rows; commutative reduce)
template <int CTRL>
__device__ __forceinline__ unsigned long long dppmax(unsigned long long v) {
    int lo = (int)(unsigned)(v & 0xFFFFFFFFull);
    int hi = (int)(unsigned)(v >> 32);
    int lo2 = __builtin_amdgcn_update_dpp(0, lo, CTRL, 0xF, 0xF, false);
    int hi2 = __builtin_amdgcn_update_dpp(0, hi, CTRL, 0xF, 0xF, false);
    unsigned long long o = ((unsigned long long)(unsigned)hi2 << 32) | (unsigned)lo2;
    return o > v ? o : v;
}
// DPP row-rotate max carrying winner coordinates as payload
template <int CTRL>
__device__ __forceinline__ void redstep(unsigned long long& v, float& x, float& y, float& z) {
    int lo2 = __builtin_amdgcn_update_dpp(0, (int)(unsigned)(v & 0xFFFFFFFFull), CTRL, 0xF, 0xF, false);
    int hi2 = __builtin_amdgcn_update_dpp(0, (int)(unsigned)(v >> 32), CTRL, 0xF, 0xF, false);
    int x2 = __builtin_amdgcn_update_dpp(0, __float_as_int(x), CTRL, 0xF, 0xF, false);
    int y2 = __builtin_amdgcn_update_dpp(0, __float_as_int(y), CTRL, 0xF, 0xF, false);
    int z2 = __builtin_amdgcn_update_dpp(0, __float_as_int(z), CTRL, 0xF, 0xF, false);
    unsigned long long o = ((unsigned long long)(unsigned)hi2 << 32) | (unsigned)(unsigned)lo2;
    if (o > v) { v = o; x = __int_as_float(x2); y = __int_as_float(y2); z = __int_as_float(z2); }
}
#define ROR1 0x121
#define ROR2 0x122
#define ROR4 0x124
#define ROR8 0x128

// ---------------- FPS: N=4096 -> 256 (all threads) then 256 -> 128 (wave 0 tail) -------
// One block/batch, 256 threads. Post-barrier reduce carries winner coords (no dependent
// s4[vi] load on the critical path: slot writers prefetch row-winner coords pre-barrier).
__global__ __launch_bounds__(256) void fps1_kernel(const float* __restrict__ xyz,
                                                   float* __restrict__ nxz,
                                                   float* __restrict__ nxz2) {
    const int b = blockIdx.x, tid = threadIdx.x;
    const int lane = tid & 63, wv = tid >> 6;      // 4 waves
    const float* X = xyz + (size_t)b * (N1 * 3);
    __shared__ float4 s4[N1];                      // 64 KB
    __shared__ unsigned long long slots_v[2][16];
    __shared__ float4 slots_c[2][16];
    __shared__ float hist[S1 * 3];
    __shared__ float4 shist[S1];
    float px[16], py[16], pz[16], md[16];
    int bidx[16];
#pragma unroll
    for (int j = 0; j < 16; ++j) {
        int i = tid + 256 * j;
        float x = X[i * 3 + 0], y = X[i * 3 + 1], z = X[i * 3 + 2];
        s4[i] = make_float4(x, y, z, 0.f);
        px[j] = x; py[j] = y; pz[j] = z;
        md[j] = 1e10f;
        bidx[j] = i;
    }
    if (tid == 0) { hist[0] = X[0]; hist[1] = X[1]; hist[2] = X[2]; }
    __syncthreads();
    float lx = X[0], ly = X[1], lz = X[2];
    for (int t = 1; t < S1; ++t) {
        float bv = -1.0f; int bi = 0;
#pragma unroll
        for (int j = 0; j < 16; ++j) {
            float d = sqdist(px[j], py[j], pz[j], lx, ly, lz);
            float m = fminf(md[j], d);
            md[j] = m;
            if (m > bv) { bv = m; bi = bidx[j]; }   // ascending flat idx: first max kept
        }
        unsigned long long best = packvi(bv, bi);
        best = dppmax<ROR1>(best);
        best = dppmax<ROR2>(best);
        best = dppmax<ROR4>(best);
        best = dppmax<ROR8>(best);                  // row (16-lane) winner
        if ((lane & 15) == 0) {
            int vi = (int)(~(unsigned)best);
            slots_v[t & 1][wv * 4 + (lane >> 4)] = best;
            slots_c[t & 1][wv * 4 + (lane >> 4)] = s4[vi];  // latency hides in barrier wait
        }
        __syncthreads();
        unsigned long long v = slots_v[t & 1][lane & 15];
        float4 c = slots_c[t & 1][lane & 15];
        float x = c.x, y = c.y, z = c.z;
        redstep<ROR1>(v, x, y, z);
        redstep<ROR2>(v, x, y, z);
        redstep<ROR4>(v, x, y, z);
        redstep<ROR8>(v, x, y, z);
        lx = x; ly = y; lz = z;                     // all lanes converge to global winner
        if (tid == 0) { hist[t * 3 + 0] = lx; hist[t * 3 + 1] = ly; hist[t * 3 + 2] = lz; }
    }
    __syncthreads();
    for (int u = tid; u < S1 * 3; u += 256) nxz[(size_t)b * S1 * 3 + u] = hist[u];
    // ---- inline FPS2 (256 -> 128), wave 0 only; hist stable after the barrier ----
    if (wv == 0) {
        float p2x[4], p2y[4], p2z[4], m2[4];
        int b2i[4];
#pragma unroll
        for (int j = 0; j < 4; ++j) {
            int i = lane + 64 * j;
            float x = hist[i * 3 + 0], y = hist[i * 3 + 1], z = hist[i * 3 + 2];
            shist[i] = make_float4(x, y, z, 0.f);
            p2x[j] = x; p2y[j] = y; p2z[j] = z;
            m2[j] = 1e10f;
            b2i[j] = i;
        }
        if (lane == 0) {
            nxz2[(size_t)b * S2 * 3 + 0] = hist[0];
            nxz2[(size_t)b * S2 * 3 + 1] = hist[1];
            nxz2[(size_t)b * S2 * 3 + 2] = hist[2];
        }
        float cx = hist[0], cy = hist[1], cz = hist[2];
        for (int t = 1; t < S2; ++t) {
            float bv = -1.0f; int bi = 0;
#pragma unroll
            for (int j = 0; j < 4; ++j) {
                float d = sqdist(p2x[j], p2y[j], p2z[j], cx, cy, cz);
                float m = fminf(m2[j], d);
                m2[j] = m;
                if (m > bv) { bv = m; bi = b2i[j]; }
            }
            unsigned long long best = packvi(bv, bi);
            best = dppmax<ROR1>(best);
            best = dppmax<ROR2>(best);
            best = dppmax<ROR4>(best);
            best = dppmax<ROR8>(best);
            { unsigned long long o = __shfl_xor(best, 16); best = o > best ? o : best; }
            { unsigned long long o = __shfl_xor(best, 32); best = o > best ? o : best; }
            int vi = (int)(~(unsigned)best);
            float4 c = shist[vi];
            cx = c.x; cy = c.y; cz = c.z;
            if (lane == 0) {
                float* dst = nxz2 + ((size_t)b * S2 + t) * 3;
                dst[0] = cx; dst[1] = cy; dst[2] = cz;
            }
        }
    }
}

// ---------------- Ball query 1 (wave-per-center): 4096 pts, r=0.2 ----------
__global__ __launch_bounds__(256) void ballq1_kernel(const float* __restrict__ xyz,
                                                     const float* __restrict__ nxz,
                                                     int* __restrict__ gidx) {
    const int wid = (blockIdx.x * 256 + threadIdx.x) >> 6;
    const int lane = threadIdx.x & 63;
    const int b = wid >> 8;
    const float* X = xyz + (size_t)b * (N1 * 3);
    const float* C = nxz + (size_t)wid * 3;
    const float cx = C[0], cy = C[1], cz = C[2];
    const float r2 = (float)(0.2 * 0.2);
    int* G = gidx + (size_t)wid * KNB;
    int cnt = 0, first = 0;
    bool found = false;
    for (int j0 = 0; j0 < N1 && cnt < KNB; j0 += 64) {
        int j = j0 + lane;
        float d2 = sqdist(cx, cy, cz, X[j * 3 + 0], X[j * 3 + 1], X[j * 3 + 2]);
        bool hit = d2 < r2;
        unsigned long long mask = __ballot(hit);
        if (!found && mask) { first = j0 + __builtin_ctzll(mask); found = true; }
        if (hit) {
            int pos = cnt + __popcll(mask & ((1ull << lane) - 1ull));
            if (pos < KNB) G[pos] = j;
        }
        cnt += __popcll(mask);
    }
    if (cnt < KNB) {
        int pad = found ? first : 0;
        if (lane >= cnt && lane < KNB) G[lane] = pad;
    }
}

// ---------------- Ball query 2 (wave-per-center): 256 pts, r=0.4 ----------
__global__ __launch_bounds__(256) void ballq2_kernel(const float* __restrict__ xyz1,
                                                     const float* __restrict__ nxz2,
                                                     int* __restrict__ gidx) {
    const int wid = (blockIdx.x * 256 + threadIdx.x) >> 6;
    const int lane = threadIdx.x & 63;
    const int b = wid >> 7;
    const float* X = xyz1 + (size_t)b * (S1 * 3);
    const float* C = nxz2 + (size_t)wid * 3;
    const float cx = C[0], cy = C[1], cz = C[2];
    const float r2 = (float)(0.4 * 0.4);
    int* G = gidx + (size_t)wid * KNB;
    int cnt = 0, first = 0;
    bool found = false;
    for (int j0 = 0; j0 < S1 && cnt < KNB; j0 += 64) {
        int j = j0 + lane;
        float d2 = sqdist(cx, cy, cz, X[j * 3 + 0], X[j * 3 + 1], X[j * 3 + 2]);
        bool hit = d2 < r2;
        unsigned long long mask = __ballot(hit);
        if (!found && mask) { first = j0 + __builtin_ctzll(mask); found = true; }
        if (hit) {
            int pos = cnt + __popcll(mask & ((1ull << lane) - 1ull));
            if (pos < KNB) G[pos] = j;
        }
        cnt += __popcll(mask);
    }
    if (cnt < KNB) {
        int pad = found ? first : 0;
        if (lane >= cnt && lane < KNB) G[lane] = pad;
    }
}

// ---------------- Weight conversion: fp32 -> bf16 arena, K padded to x64 ----------------
//  w11b@0      64x64   | w12b@4096  128x64 | w20p@12288 128x192 (PERM: feat-first)
//  w21b@36864  128x128 | w22b@53248 256x128| w30p@86016 256x320 (PERM: feat-first)
//  w31b@167936 512x256 | w32b@299008 1024x512  total 823296
__global__ __launch_bounds__(256) void wconv_kernel(
    const float* __restrict__ w11, const float* __restrict__ w12,
    const float* __restrict__ w20, const float* __restrict__ w21,
    const float* __restrict__ w22, const float* __restrict__ w30,
    const float* __restrict__ w31, const float* __restrict__ w32,
    unsigned short* __restrict__ wb) {
    int u = blockIdx.x * 256 + threadIdx.x;
    if (u >= 823296) return;
    const float* src; int base, Kp, Ko; int perm = 0;   // perm: feature-count for feat-first layout
    if      (u < 4096)   { src = w11; base = 0;      Kp = 64;  Ko = 64;  }
    else if (u < 12288)  { src = w12; base = 4096;   Kp = 64;  Ko = 64;  }
    else if (u < 36864)  { src = w20; base = 12288;  Kp = 192; Ko = 131; perm = 128; }
    else if (u < 53248)  { src = w21; base = 36864;  Kp = 128; Ko = 128; }
    else if (u < 86016)  { src = w22; base = 53248;  Kp = 128; Ko = 128; }
    else if (u < 167936) { src = w30; base = 86016;  Kp = 320; Ko = 259; perm = 256; }
    else if (u < 299008) { src = w31; base = 167936; Kp = 256; Ko = 256; }
    else                 { src = w32; base = 299008; Kp = 512; Ko = 512; }
    int local = u - base;
    int n = local / Kp, k = local - n * Kp;
    float v;
    if (perm) {
        int ksrc = (k < perm) ? (k + 3) : ((k < perm + 3) ? (k - perm) : -1);
        v = (ksrc >= 0) ? src[(size_t)n * Ko + ksrc] : 0.f;
    } else {
        v = (k < Ko) ? src[(size_t)n * Ko + k] : 0.f;
    }
    wb[u] = f2bf(v);
}

// ---------------- Module 1 fused: gather + L0(K=3, VALU) + L1 + L2 MFMA + pool ---------
__global__ __launch_bounds__(256) void m1_kernel(
    const float* __restrict__ xyz, const float* __restrict__ nxz,
    const int* __restrict__ g1,
    const float* __restrict__ w10, const float* __restrict__ b10,
    const unsigned short* __restrict__ w11b, const float* __restrict__ b11,
    const unsigned short* __restrict__ w12b, const float* __restrict__ b12,
    unsigned short* __restrict__ f1) {
    constexpr int AP = 72;
    __shared__ __align__(16) unsigned short As[128 * AP];
    __shared__ __align__(16) unsigned short Hs[128 * AP];
    __shared__ __align__(16) unsigned short Bs[128 * AP];
    __shared__ float sxyz[128 * 3];
    const int t = threadIdx.x;
    const int lane = t & 63, w = t >> 6;
    const int r16 = lane & 15, q = lane >> 4;
    const int m0 = blockIdx.x * 128;

    if (t < 128) {
        int row = m0 + t, bs = row >> 5, b = bs >> 8, j = g1[row];
        const float* P = xyz + ((size_t)b * N1 + j) * 3;
        const float* Cc = nxz + (size_t)bs * 3;
        sxyz[t * 3 + 0] = P[0] - Cc[0];
        sxyz[t * 3 + 1] = P[1] - Cc[1];
        sxyz[t * 3 + 2] = P[2] - Cc[2];
    }
    for (int c = t; c < 64 * 8; c += 256) {
        int row = c >> 3, ch = c & 7;
        *(short8*)&Bs[row * AP + ch * 8] = *(const short8*)&w11b[row * 64 + ch * 8];
    }
    __syncthreads();
    {
        const int r = t >> 1, half = (t & 1) * 32;
        const float x = sxyz[r * 3 + 0], y = sxyz[r * 3 + 1], z = sxyz[r * 3 + 2];
        unsigned short tmp[32];
#pragma unroll
        for (int o = 0; o < 32; ++o) {
            int oo = half + o;
            float acc = b10[oo];
            acc = fmaf(x, w10[oo * 3 + 0], acc);
            acc = fmaf(y, w10[oo * 3 + 1], acc);
            acc = fmaf(z, w10[oo * 3 + 2], acc);
            tmp[o] = f2bf(fmaxf(acc, 0.f));
        }
#pragma unroll
        for (int c2 = 0; c2 < 4; ++c2)
            *(short8*)&As[r * AP + half + c2 * 8] = *(short8*)&tmp[c2 * 8];
    }
    __syncthreads();
    {
        f32x4 acc[2][4];
#pragma unroll
        for (int i = 0; i < 2; ++i)
#pragma unroll
            for (int j = 0; j < 4; ++j) acc[i][j] = (f32x4){0.f, 0.f, 0.f, 0.f};
#pragma unroll
        for (int kk = 0; kk < 64; kk += 32) {
            short8 a0 = *(const short8*)&As[(w * 32 + r16) * AP + kk + q * 8];
            short8 a1 = *(const short8*)&As[(w * 32 + 16 + r16) * AP + kk + q * 8];
#pragma unroll
            for (int j = 0; j < 4; ++j) {
                short8 bf = *(const short8*)&Bs[(j * 16 + r16) * AP + kk + q * 8];
                acc[0][j] = __builtin_amdgcn_mfma_f32_16x16x32_bf16(a0, bf, acc[0][j], 0, 0, 0);
                acc[1][j] = __builtin_amdgcn_mfma_f32_16x16x32_bf16(a1, bf, acc[1][j], 0, 0, 0);
            }
        }
#pragma unroll
        for (int i = 0; i < 2; ++i)
#pragma unroll
            for (int j = 0; j < 4; ++j) {
                int col = j * 16 + r16;
                float bv = b11[col];
#pragma unroll
                for (int r = 0; r < 4; ++r) {
                    int row = w * 32 + i * 16 + q * 4 + r;
                    Hs[row * AP + col] = f2bf(fmaxf(acc[i][j][r] + bv, 0.f));
                }
            }
    }
    __syncthreads();
    for (int c = t; c < 128 * 8; c += 256) {
        int row = c >> 3, ch = c & 7;
        *(short8*)&Bs[row * AP + ch * 8] = *(const short8*)&w12b[row * 64 + ch * 8];
    }
    __syncthreads();
    {
        f32x4 acc[2][8];
#pragma unroll
        for (int i = 0; i < 2; ++i)
#pragma unroll
            for (int j = 0; j < 8; ++j) acc[i][j] = (f32x4){0.f, 0.f, 0.f, 0.f};
#pragma unroll
        for (int kk = 0; kk < 64; kk += 32) {
            short8 a0 = *(const short8*)&Hs[(w * 32 + r16) * AP + kk + q * 8];
            short8 a1 = *(const short8*)&Hs[(w * 32 + 16 + r16) * AP + kk + q * 8];
#pragma unroll
            for (int j = 0; j < 8; ++j) {
                short8 bf = *(const short8*)&Bs[(j * 16 + r16) * AP + kk + q * 8];
                acc[0][j] = __builtin_amdgcn_mfma_f32_16x16x32_bf16(a0, bf, acc[0][j], 0, 0, 0);
                acc[1][j] = __builtin_amdgcn_mfma_f32_16x16x32_bf16(a1, bf, acc[1][j], 0, 0, 0);
            }
        }
#pragma unroll
        for (int j = 0; j < 8; ++j) {
            int col = j * 16 + r16;
            float bv = b12[col];
            float mv = 0.f;
#pragma unroll
            for (int i = 0; i < 2; ++i)
#pragma unroll
                for (int r = 0; r < 4; ++r)
                    mv = fmaxf(mv, acc[i][j][r] + bv);
            mv = fmaxf(mv, __shfl_xor(mv, 16));
            mv = fmaxf(mv, __shfl_xor(mv, 32));
            if (q == 0)
                f1[(size_t)((m0 >> 5) + w) * 128 + col] = f2bf(mv);
        }
    }
}

// ---------------- Module 2 fully fused: gather + L0(192) + L1(128) + L2(256)+pool ----
__global__ __launch_bounds__(256) void m2_kernel(
    const float* __restrict__ xyz1, const float* __restrict__ nxz2,
    const int* __restrict__ g2, const unsigned short* __restrict__ f1,
    const unsigned short* __restrict__ w20p, const float* __restrict__ b20,
    const unsigned short* __restrict__ w21b, const float* __restrict__ b21,
    const unsigned short* __restrict__ w22b, const float* __restrict__ b22,
    unsigned short* __restrict__ f2) {
    constexpr int AP = 72, HP = 136;
    __shared__ __align__(16) unsigned short smem[36864];   // 72 KB
    unsigned short* R1 = smem;
    unsigned short* R2 = smem + 18432;
    unsigned short* As = R1;
    unsigned short* Bs = R1 + 9216;
    unsigned short* H1 = R2;
    unsigned short* H2 = R1;
    unsigned short* Bs2 = R2;
    __shared__ int ribase[128];
    __shared__ unsigned short sxb[128 * 3];
    const int t = threadIdx.x;
    const int lane = t & 63, w = t >> 6;
    const int r16 = lane & 15, q = lane >> 4;
    const int m0 = blockIdx.x * 128;

    if (t < 128) {
        int row = m0 + t, bs = row >> 5, b = bs >> 7, j = g2[row];
        ribase[t] = (b * 256 + j) * 128;
        const float* P = xyz1 + ((size_t)b * S1 + j) * 3;
        const float* Cc = nxz2 + (size_t)bs * 3;
        sxb[t * 3 + 0] = f2bf(P[0] - Cc[0]);
        sxb[t * 3 + 1] = f2bf(P[1] - Cc[1]);
        sxb[t * 3 + 2] = f2bf(P[2] - Cc[2]);
    }
    __syncthreads();

    // ---- L0: K=192 (3 tiles), N=128 ----
    f32x4 acc[2][8];
#pragma unroll
    for (int i = 0; i < 2; ++i)
#pragma unroll
        for (int j = 0; j < 8; ++j) acc[i][j] = (f32x4){0.f, 0.f, 0.f, 0.f};
    for (int kt = 0; kt < 3; ++kt) {
        const int k0 = kt * 64;
        if (kt < 2) {
            for (int c = t; c < 128 * 8; c += 256) {
                int row = c >> 3, ch = c & 7;
                *(short8*)&As[row * AP + ch * 8] =
                    *(const short8*)&f1[(size_t)ribase[row] + k0 + ch * 8];
            }
        } else {
            for (int c = t; c < 128 * 8; c += 256) {
                int row = c >> 3, ch = c & 7;
                short8 v = (short8){0, 0, 0, 0, 0, 0, 0, 0};
                if (ch == 0) {
                    v[0] = (short)sxb[row * 3 + 0];
                    v[1] = (short)sxb[row * 3 + 1];
                    v[2] = (short)sxb[row * 3 + 2];
                }
                *(short8*)&As[row * AP + ch * 8] = v;
            }
        }
        for (int c = t; c < 128 * 8; c += 256) {
            int row = c >> 3, ch = c & 7;
            *(short8*)&Bs[row * AP + ch * 8] =
                *(const short8*)&w20p[(size_t)row * 192 + k0 + ch * 8];
        }
        __syncthreads();
#pragma unroll
        for (int kk = 0; kk < 64; kk += 32) {
            short8 a0 = *(const short8*)&As[(w * 32 + r16) * AP + kk + q * 8];
            short8 a1 = *(const short8*)&As[(w * 32 + 16 + r16) * AP + kk + q * 8];
#pragma unroll
            for (int j = 0; j < 8; ++j) {
                short8 bf = *(const short8*)&Bs[(j * 16 + r16) * AP + kk + q * 8];
                acc[0][j] = __builtin_amdgcn_mfma_f32_16x16x32_bf16(a0, bf, acc[0][j], 0, 0, 0);
                acc[1][j] = __builtin_amdgcn_mfma_f32_16x16x32_bf16(a1, bf, acc[1][j], 0, 0, 0);
            }
        }
        __syncthreads();
    }
#pragma unroll
    for (int i = 0; i < 2; ++i)
#pragma unroll
        for (int j = 0; j < 8; ++j) {
            int col = j * 16 + r16;
            float bv = b20[col];
#pragma unroll
            for (int r = 0; r < 4; ++r) {
                int row = w * 32 + i * 16 + q * 4 + r;
                H1[row * HP + col] = f2bf(fmaxf(acc[i][j][r] + bv, 0.f));
            }
        }
    __syncthreads();

    // ---- L1: K=128 (2 tiles), N=128 ----
#pragma unroll
    for (int i = 0; i < 2; ++i)
#pragma unroll
        for (int j = 0; j < 8; ++j) acc[i][j] = (f32x4){0.f, 0.f, 0.f, 0.f};
    for (int kt = 0; kt < 2; ++kt) {
        const int k0 = kt * 64;
        for (int c = t; c < 128 * 8; c += 256) {
            int row = c >> 3, ch = c & 7;
            *(short8*)&As[row * AP + ch * 8] =
                *(const short8*)&w21b[(size_t)row * 128 + k0 + ch * 8];
        }
        __syncthreads();
#pragma unroll
        for (int kk = 0; kk < 64; kk += 32) {
            short8 a0 = *(const short8*)&H1[(w * 32 + r16) * HP + k0 + kk + q * 8];
            short8 a1 = *(const short8*)&H1[(w * 32 + 16 + r16) * HP + k0 + kk + q * 8];
#pragma unroll
            for (int j = 0; j < 8; ++j) {
                short8 bf = *(const short8*)&As[(j * 16 + r16) * AP + kk + q * 8];
                acc[0][j] = __builtin_amdgcn_mfma_f32_16x16x32_bf16(a0, bf, acc[0][j], 0, 0, 0);
                acc[1][j] = __builtin_amdgcn_mfma_f32_16x16x32_bf16(a1, bf, acc[1][j], 0, 0, 0);
            }
        }
        __syncthreads();
    }
#pragma unroll
    for (int i = 0; i < 2; ++i)
#pragma unroll
        for (int j = 0; j < 8; ++j) {
            int col = j * 16 + r16;
            float bv = b21[col];
#pragma unroll
            for (int r = 0; r < 4; ++r) {
                int row = w * 32 + i * 16 + q * 4 + r;
                H2[row * HP + col] = f2bf(fmaxf(acc[i][j][r] + bv, 0.f));
            }
        }
    __syncthreads();

    // ---- L2: K=128 (2 tiles), N=256 + pool ----
    f32x4 acc2[2][16];
#pragma unroll
    for (int i = 0; i < 2; ++i)
#pragma unroll
        for (int j = 0; j < 16; ++j) acc2[i][j] = (f32x4){0.f, 0.f, 0.f, 0.f};
    for (int kt = 0; kt < 2; ++kt) {
        const int k0 = kt * 64;
        for (int c = t; c < 256 * 8; c += 256) {
            int row = c >> 3, ch = c & 7;
            *(short8*)&Bs2[row * AP + ch * 8] =
                *(const short8*)&w22b[(size_t)row * 128 + k0 + ch * 8];
        }
        __syncthreads();
#pragma unroll
        for (int kk = 0; kk < 64; kk += 32) {
            short8 a0 = *(const short8*)&H2[(w * 32 + r16) * HP + k0 + kk + q * 8];
            short8 a1 = *(const short8*)&H2[(w * 32 + 16 + r16) * HP + k0 + kk + q * 8];
#pragma unroll
            for (int j = 0; j < 16; ++j) {
                short8 bf = *(const short8*)&Bs2[(j * 16 + r16) * AP + kk + q * 8];
                acc2[0][j] = __builtin_amdgcn_mfma_f32_16x16x32_bf16(a0, bf, acc2[0][j], 0, 0, 0);
                acc2[1][j] = __builtin_amdgcn_mfma_f32_16x16x32_bf16(a1, bf, acc2[1][j], 0, 0, 0);
            }
        }
        __syncthreads();
    }
#pragma unroll
    for (int j = 0; j < 16; ++j) {
        int col = j * 16 + r16;
        float bv = b22[col];
        float mv = 0.f;
#pragma unroll
        for (int i = 0; i < 2; ++i)
#pragma unroll
            for (int r = 0; r < 4; ++r)
                mv = fmaxf(mv, acc2[i][j][r] + bv);
        mv = fmaxf(mv, __shfl_xor(mv, 16));
        mv = fmaxf(mv, __shfl_xor(mv, 32));
        if (q == 0)
            f2[(size_t)((m0 >> 5) + w) * 256 + col] = f2bf(mv);
    }
}

// ---------------- Module 3 layer 0 with fused concat (feat-first K=320) ---------------
__global__ __launch_bounds__(256) void l30_kernel(
    const float* __restrict__ nxz2, const unsigned short* __restrict__ f2,
    const unsigned short* __restrict__ w30p, const float* __restrict__ bias,
    unsigned short* __restrict__ C) {
    constexpr int AP = 72;
    __shared__ __align__(16) unsigned short As[128 * AP];
    __shared__ __align__(16) unsigned short Bs[128 * AP];
    const int t = threadIdx.x;
    const int lane = t & 63, w = t >> 6;
    const int r16 = lane & 15, q = lane >> 4;
    const int m0 = blockIdx.x * 128;
    const int n0 = blockIdx.y * 128;

    f32x4 acc[2][8];
#pragma unroll
    for (int i = 0; i < 2; ++i)
#pragma unroll
        for (int j = 0; j < 8; ++j) acc[i][j] = (f32x4){0.f, 0.f, 0.f, 0.f};

    for (int kt = 0; kt < 5; ++kt) {
        const int k0 = kt * 64;
        if (kt < 4) {
            for (int c = t; c < 128 * 8; c += 256) {
                int row = c >> 3, ch = c & 7;
                *(short8*)&As[row * AP + ch * 8] =
                    *(const short8*)&f2[(size_t)(m0 + row) * 256 + k0 + ch * 8];
            }
        } else {
            for (int c = t; c < 128 * 8; c += 256) {
                int row = c >> 3, ch = c & 7;
                short8 v = (short8){0, 0, 0, 0, 0, 0, 0, 0};
                if (ch == 0) {
                    const float* P = nxz2 + (size_t)(m0 + row) * 3;
                    v[0] = (short)f2bf(P[0]);
                    v[1] = (short)f2bf(P[1]);
                    v[2] = (short)f2bf(P[2]);
                }
                *(short8*)&As[row * AP + ch * 8] = v;
            }
        }
        for (int c = t; c < 128 * 8; c += 256) {
            int row = c >> 3, ch = c & 7;
            *(short8*)&Bs[row * AP + ch * 8] =
                *(const short8*)&w30p[(size_t)(n0 + row) * 320 + k0 + ch * 8];
        }
        __syncthreads();
#pragma unroll
        for (int kk = 0; kk < 64; kk += 32) {
            short8 a0 = *(const short8*)&As[(w * 32 + r16) * AP + kk + q * 8];
            short8 a1 = *(const short8*)&As[(w * 32 + 16 + r16) * AP + kk + q * 8];
#pragma unroll
            for (int j = 0; j < 8; ++j) {
                short8 bf = *(const short8*)&Bs[(j * 16 + r16) * AP + kk + q * 8];
                acc[0][j] = __builtin_amdgcn_mfma_f32_16x16x32_bf16(a0, bf, acc[0][j], 0, 0, 0);
                acc[1][j] = __builtin_amdgcn_mfma_f32_16x16x32_bf16(a1, bf, acc[1][j], 0, 0, 0);
            }
        }
        __syncthreads();
    }
#pragma unroll
    for (int i = 0; i < 2; ++i)
#pragma unroll
        for (int j = 0; j < 8; ++j) {
            int col = n0 + j * 16 + r16;
            float bv = bias[col];
#pragma unroll
            for (int r = 0; r < 4; ++r) {
                int row = m0 + w * 32 + i * 16 + q * 4 + r;
                C[(size_t)row * 256 + col] = f2bf(fmaxf(acc[i][j][r] + bv, 0.f));
            }
        }
}

// ---------------- bf16 MFMA GEMM (BM templated): C = relu(X*W^T + bias), BN=128 --------
template <int BM_>
__global__ __launch_bounds__(256) void mfma_gemm(const unsigned short* __restrict__ X,
                                                 const unsigned short* __restrict__ W,
                                                 const float* __restrict__ bias,
                                                 unsigned short* __restrict__ C,
                                                 int M, int N, int K) {
    constexpr int BK = 64, AP = BK + 8;
    constexpr int RW = BM_ / 64;         // M-frags per wave
    constexpr int WR = BM_ / 4;          // rows per wave
    __shared__ __align__(16) unsigned short As[BM_ * AP];
    __shared__ __align__(16) unsigned short Bs[128 * AP];
    const int t = threadIdx.x;
    const int lane = t & 63, w = t >> 6;
    const int m0 = blockIdx.x * BM_;
    const int n0 = blockIdx.y * 128;
    const int r16 = lane & 15, q = lane >> 4;

    f32x4 acc[RW][8];
#pragma unroll
    for (int i = 0; i < RW; ++i)
#pragma unroll
        for (int j = 0; j < 8; ++j) acc[i][j] = (f32x4){0.f, 0.f, 0.f, 0.f};

    for (int k0 = 0; k0 < K; k0 += BK) {
        for (int c = t; c < BM_ * 8; c += 256) {
            int row = c >> 3, ch = c & 7;
            *(short8*)&As[row * AP + ch * 8] =
                *(const short8*)&X[(size_t)(m0 + row) * K + k0 + ch * 8];
        }
        for (int c = t; c < 128 * 8; c += 256) {
            int row = c >> 3, ch = c & 7;
            *(short8*)&Bs[row * AP + ch * 8] =
                *(const short8*)&W[(size_t)(n0 + row) * K + k0 + ch * 8];
        }
        __syncthreads();
#pragma unroll
        for (int kk = 0; kk < BK; kk += 32) {
            short8 a[RW];
#pragma unroll
            for (int i = 0; i < RW; ++i)
                a[i] = *(const short8*)&As[(w * WR + i * 16 + r16) * AP + kk + q * 8];
#pragma unroll
            for (int j = 0; j < 8; ++j) {
                short8 bf = *(const short8*)&Bs[(j * 16 + r16) * AP + kk + q * 8];
#pragma unroll
                for (int i = 0; i < RW; ++i)
                    acc[i][j] = __builtin_amdgcn_mfma_f32_16x16x32_bf16(a[i], bf, acc[i][j], 0, 0, 0);
            }
        }
        __syncthreads();
    }
#pragma unroll
    for (int i = 0; i < RW; ++i)
#pragma unroll
        for (int j = 0; j < 8; ++j) {
            int col = n0 + j * 16 + r16;
            float bv = bias[col];
#pragma unroll
            for (int r = 0; r < 4; ++r) {
                int row = m0 + w * WR + i * 16 + q * 4 + r;
                C[(size_t)row * N + col] = f2bf(fmaxf(acc[i][j][r] + bv, 0.f));
            }
        }
}

// ---------------- Final GEMM (N=1024, K=512) + max over 128 rows -> fp32 out ----------
// BM=128 = one batch per block-row; pooled output out[batch][n0+col].
__global__ __launch_bounds__(256) void gemm_pool128(const unsigned short* __restrict__ X,
                                                    const unsigned short* __restrict__ W,
                                                    const float* __restrict__ bias,
                                                    float* __restrict__ out) {
    constexpr int BK = 64, AP = BK + 8, K = 512;
    __shared__ __align__(16) unsigned short As[128 * AP];
    __shared__ __align__(16) unsigned short Bs[128 * AP];
    __shared__ float pool[4][128];
    const int t = threadIdx.x;
    const int lane = t & 63, w = t >> 6;
    const int m0 = blockIdx.x * 128;
    const int n0 = blockIdx.y * 128;
    const int r16 = lane & 15, q = lane >> 4;

    f32x4 acc[2][8];
#pragma unroll
    for (int i = 0; i < 2; ++i)
#pragma unroll
        for (int j = 0; j < 8; ++j) acc[i][j] = (f32x4){0.f, 0.f, 0.f, 0.f};

    for (int k0 = 0; k0 < K; k0 += BK) {
        for (int c = t; c < 128 * 8; c += 256) {
            int row = c >> 3, ch = c & 7;
            *(short8*)&As[row * AP + ch * 8] =
                *(const short8*)&X[(size_t)(m0 + row) * K + k0 + ch * 8];
        }
        for (int c = t; c < 128 * 8; c += 256) {
            int row = c >> 3, ch = c & 7;
            *(short8*)&Bs[row * AP + ch * 8] =
                *(const short8*)&W[(size_t)(n0 + row) * K + k0 + ch * 8];
        }
        __syncthreads();
#pragma unroll
        for (int kk = 0; kk < BK; kk += 32) {
            short8 a0 = *(const short8*)&As[(w * 32 + r16) * AP + kk + q * 8];
            short8 a1 = *(const short8*)&As[(w * 32 + 16 + r16) * AP + kk + q * 8];
#pragma unroll
            for (int j = 0; j < 8; ++j) {
                short8 bf = *(const short8*)&Bs[(j * 16 + r16) * AP + kk + q * 8];
                acc[0][j] = __builtin_amdgcn_mfma_f32_16x16x32_bf16(a0, bf, acc[0][j], 0, 0, 0);
                acc[1][j] = __builtin_amdgcn_mfma_f32_16x16x32_bf16(a1, bf, acc[1][j], 0, 0, 0);
            }
        }
        __syncthreads();
    }
    // wave-level pool over its 32 rows (relu via 0-init), then cross-wave via LDS
#pragma unroll
    for (int j = 0; j < 8; ++j) {
        float bv = bias[n0 + j * 16 + r16];
        float mv = 0.f;
#pragma unroll
        for (int i = 0; i < 2; ++i)
#pragma unroll
            for (int r = 0; r < 4; ++r)
                mv = fmaxf(mv, acc[i][j][r] + bv);
        mv = fmaxf(mv, __shfl_xor(mv, 16));
        mv = fmaxf(mv, __shfl_xor(mv, 32));
        if (q == 0) pool[w][j * 16 + r16] = mv;
    }
    __syncthreads();
    if (t < 128) {
        float m = fmaxf(fmaxf(pool[0][t], pool[1][t]), fmaxf(pool[2][t], pool[3][t]));
        out[(size_t)blockIdx.x * 1024 + n0 + t] = m;
    }
}

extern "C" void kernel_launch(void* const* d_in, const int* in_sizes, int n_in,
                              void* d_out, int out_size, void* d_ws, size_t ws_size,
                              hipStream_t stream) {
    const float* data = (const float*)d_in[0];
    const float* w10 = (const float*)d_in[1];  const float* b10 = (const float*)d_in[2];
    const float* w11 = (const float*)d_in[3];  const float* b11 = (const float*)d_in[4];
    const float* w12 = (const float*)d_in[5];  const float* b12 = (const float*)d_in[6];
    const float* w20 = (const float*)d_in[7];  const float* b20 = (const float*)d_in[8];
    const float* w21 = (const float*)d_in[9];  const float* b21 = (const float*)d_in[10];
    const float* w22 = (const float*)d_in[11]; const float* b22 = (const float*)d_in[12];
    const float* w30 = (const float*)d_in[13]; const float* b30 = (const float*)d_in[14];
    const float* w31 = (const float*)d_in[15]; const float* b31 = (const float*)d_in[16];
    const float* w32 = (const float*)d_in[17]; const float* b32 = (const float*)d_in[18];
    float* out = (float*)d_out;

    char* ws = (char*)d_ws;
    size_t off = 0;
    auto alloc = [&](size_t bytes) -> void* {
        void* p = ws + off;
        off += (bytes + 255) & ~(size_t)255;
        return p;
    };
    float* nxz1 = (float*)alloc((size_t)BT * S1 * 3 * 4);
    int*   g1   = (int*)  alloc((size_t)BT * S1 * KNB * 4);
    float* nxz2 = (float*)alloc((size_t)BT * S2 * 3 * 4);
    int*   g2   = (int*)  alloc((size_t)BT * S2 * KNB * 4);
    unsigned short* wb  = (unsigned short*)alloc((size_t)823296 * 2);
    unsigned short* f1  = (unsigned short*)alloc((size_t)8192 * 128 * 2);
    unsigned short* f2  = (unsigned short*)alloc((size_t)4096 * 256 * 2);
    unsigned short* C1  = (unsigned short*)alloc((size_t)4096 * 256 * 2);
    unsigned short* C2  = (unsigned short*)alloc((size_t)4096 * 512 * 2);

    const unsigned short* w11b = wb + 0;
    const unsigned short* w12b = wb + 4096;
    const unsigned short* w20p = wb + 12288;
    const unsigned short* w21b = wb + 36864;
    const unsigned short* w22b = wb + 53248;
    const unsigned short* w30p = wb + 86016;
    const unsigned short* w31b = wb + 167936;
    const unsigned short* w32b = wb + 299008;

    wconv_kernel<<<(823296 + 255) / 256, 256, 0, stream>>>(w11, w12, w20, w21, w22, w30, w31, w32, wb);

    // ---- module 1 (fps1 also computes fps2's centers inline) ----
    fps1_kernel<<<BT, 256, 0, stream>>>(data, nxz1, nxz2);
    ballq1_kernel<<<(BT * S1) / 4, 256, 0, stream>>>(data, nxz1, g1);
    m1_kernel<<<262144 / 128, 256, 0, stream>>>(data, nxz1, g1, w10, b10, w11b, b11, w12b, b12, f1);
    // ---- module 2 ----
    ballq2_kernel<<<(BT * S2) / 4, 256, 0, stream>>>(nxz1, nxz2, g2);
    m2_kernel<<<131072 / 128, 256, 0, stream>>>(nxz1, nxz2, g2, f1, w20p, b20, w21b, b21, w22b, b22, f2);
    // ---- module 3 ----
    l30_kernel<<<dim3(4096 / 128, 2), 256, 0, stream>>>(nxz2, f2, w30p, b30, C1);
    mfma_gemm<64><<<dim3(4096 / 64, 4), 256, 0, stream>>>(C1, w31b, b31, C2, 4096, 512, 256);
    gemm_pool128<<<dim3(4096 / 128, 8), 256, 0, stream>>>(C2, w32b, b32, out);
}

// Round 11
// 486.104 us; speedup vs baseline: 1.1854x; 1.0552x over previous
//
#include <hip/hip_runtime.h>
#include <hip/hip_bf16.h>
#include <cstdint>
#include <cstddef>

// Problem constants: data (4,8,4096,3) -> 32 batches x 4096 points
#define BT 32
#define N1 4096
#define S1 256
#define S2 128
#define KNB 32

typedef __attribute__((ext_vector_type(8))) short short8;   // 8 bf16 in 4 VGPRs
typedef __attribute__((ext_vector_type(4))) float f32x4;

__device__ __forceinline__ float sqdist(float ax, float ay, float az,
                                        float bx, float by, float bz) {
    // exact replication of sum((a-b)**2, axis=-1): mul then left-to-right add, NO fma
    float dx = __fsub_rn(ax, bx), dy = __fsub_rn(ay, by), dz = __fsub_rn(az, bz);
    return __fadd_rn(__fadd_rn(__fmul_rn(dx, dx), __fmul_rn(dy, dy)), __fmul_rn(dz, dz));
}

// bf16 round-to-nearest-even (values here are finite)
__device__ __forceinline__ unsigned short f2bf(float f) {
    unsigned u = __float_as_uint(f);
    return (unsigned short)((u + 0x7FFFu + ((u >> 16) & 1u)) >> 16);
}
__device__ __forceinline__ float bf2f(unsigned short h) {
    return __uint_as_float(((unsigned)h) << 16);
}

// pack (value, index) for argmax-with-first-index-tie-break: distances >= 0 so float
// bits are monotonic as uint; on equal value, larger ~idx == smaller idx wins.
__device__ __forceinline__ unsigned long long packvi(float v, int idx) {
    return ((unsigned long long)__float_as_uint(v) << 32) | (unsigned)(~idx);
}

// DPP row-rotate max for u64 (rotate within 16-lane rows; commutative reduce)
template <int CTRL>
__device__ __forceinline__ unsigned long long dppmax(unsigned long long v) {
    int lo = (int)(unsigned)(v & 0xFFFFFFFFull);
    int hi = (int)(unsigned)(v >> 32);
    int lo2 = __builtin_amdgcn_update_dpp(0, lo, CTRL, 0xF, 0xF, false);
    int hi2 = __builtin_amdgcn_update_dpp(0, hi, CTRL, 0xF, 0xF, false);
    unsigned long long o = ((unsigned long long)(unsigned)hi2 << 32) | (unsigned)lo2;
    return o > v ? o : v;
}
#define ROR1 0x121
#define ROR2 0x122
#define ROR4 0x124
#define ROR8 0x128

// ---------------- FPS module 1: N=4096 -> 256, one block/batch, 256 threads ----------
// (R8/R9-proven version: 153us. Slot reduce + post-barrier s4[vi] coord read.)
__global__ __launch_bounds__(256) void fps1_kernel(const float* __restrict__ xyz,
                                                   float* __restrict__ nxz) {
    const int b = blockIdx.x, tid = threadIdx.x;
    const int lane = tid & 63, wv = tid >> 6;      // 4 waves
    const float* X = xyz + (size_t)b * (N1 * 3);
    __shared__ float4 s4[N1];                      // 64 KB
    __shared__ unsigned long long slots[2][16];
    __shared__ float hist[S1 * 3];
    float px[16], py[16], pz[16], md[16];
    int bidx[16];
#pragma unroll
    for (int j = 0; j < 16; ++j) {
        int i = tid + 256 * j;
        float x = X[i * 3 + 0], y = X[i * 3 + 1], z = X[i * 3 + 2];
        s4[i] = make_float4(x, y, z, 0.f);
        px[j] = x; py[j] = y; pz[j] = z;
        md[j] = 1e10f;
        bidx[j] = i;
    }
    if (tid == 0) { hist[0] = X[0]; hist[1] = X[1]; hist[2] = X[2]; }
    __syncthreads();
    float4 c0 = s4[0];
    float lx = c0.x, ly = c0.y, lz = c0.z;
    for (int t = 1; t < S1; ++t) {
        float bv = -1.0f; int bi = 0;
#pragma unroll
        for (int j = 0; j < 16; ++j) {
            float d = sqdist(px[j], py[j], pz[j], lx, ly, lz);
            float m = fminf(md[j], d);
            md[j] = m;
            if (m > bv) { bv = m; bi = bidx[j]; }   // ascending flat idx: first max kept
        }
        unsigned long long best = packvi(bv, bi);
        best = dppmax<ROR1>(best);
        best = dppmax<ROR2>(best);
        best = dppmax<ROR4>(best);
        best = dppmax<ROR8>(best);                  // row (16-lane) max
        if ((lane & 15) == 0) slots[t & 1][wv * 4 + (lane >> 4)] = best;
        __syncthreads();
        unsigned long long w = slots[t & 1][lane & 15];
        w = dppmax<ROR1>(w);
        w = dppmax<ROR2>(w);
        w = dppmax<ROR4>(w);
        w = dppmax<ROR8>(w);
        int vi = (int)(~(unsigned)w);
        float4 c = s4[vi];
        lx = c.x; ly = c.y; lz = c.z;
        if (tid == 0) { hist[t * 3 + 0] = lx; hist[t * 3 + 1] = ly; hist[t * 3 + 2] = lz; }
    }
    __syncthreads();
    for (int u = tid; u < S1 * 3; u += 256) nxz[(size_t)b * S1 * 3 + u] = hist[u];
}

// ---------------- FPS module 2: N=256 -> 128, ONE WAVE per batch ----------
__global__ __launch_bounds__(64) void fps2_kernel(const float* __restrict__ xyz1,
                                                  float* __restrict__ nxz2) {
    const int b = blockIdx.x, lane = threadIdx.x;
    const float* X = xyz1 + (size_t)b * (S1 * 3);
    __shared__ float4 s4[S1];
    float px[4], py[4], pz[4], md[4];
    int bidx[4];
#pragma unroll
    for (int j = 0; j < 4; ++j) {
        int i = lane + 64 * j;
        float x = X[i * 3 + 0], y = X[i * 3 + 1], z = X[i * 3 + 2];
        s4[i] = make_float4(x, y, z, 0.f);
        px[j] = x; py[j] = y; pz[j] = z;
        md[j] = 1e10f;
        bidx[j] = i;
    }
    if (lane == 0) {
        nxz2[(size_t)b * S2 * 3 + 0] = X[0];
        nxz2[(size_t)b * S2 * 3 + 1] = X[1];
        nxz2[(size_t)b * S2 * 3 + 2] = X[2];
    }
    // single wave: LDS writes above are wave-synchronous
    float4 cc = s4[0];
    float lx = cc.x, ly = cc.y, lz = cc.z;
    for (int t = 1; t < S2; ++t) {
        float bv = -1.0f; int bi = 0;
#pragma unroll
        for (int j = 0; j < 4; ++j) {
            float d = sqdist(px[j], py[j], pz[j], lx, ly, lz);
            float m = fminf(md[j], d);
            md[j] = m;
            if (m > bv) { bv = m; bi = bidx[j]; }
        }
        unsigned long long best = packvi(bv, bi);
        best = dppmax<ROR1>(best);
        best = dppmax<ROR2>(best);
        best = dppmax<ROR4>(best);
        best = dppmax<ROR8>(best);
        { unsigned long long o = __shfl_xor(best, 16); best = o > best ? o : best; }
        { unsigned long long o = __shfl_xor(best, 32); best = o > best ? o : best; }
        int vi = (int)(~(unsigned)best);
        float4 c = s4[vi];
        lx = c.x; ly = c.y; lz = c.z;
        if (lane == 0) {
            float* dst = nxz2 + ((size_t)b * S2 + t) * 3;
            dst[0] = lx; dst[1] = ly; dst[2] = lz;
        }
    }
}

// ---------------- Ball query 1 (wave-per-center): 4096 pts, r=0.2 ----------
__global__ __launch_bounds__(256) void ballq1_kernel(const float* __restrict__ xyz,
                                                     const float* __restrict__ nxz,
                                                     int* __restrict__ gidx) {
    const int wid = (blockIdx.x * 256 + threadIdx.x) >> 6;
    const int lane = threadIdx.x & 63;
    const int b = wid >> 8;
    const float* X = xyz + (size_t)b * (N1 * 3);
    const float* C = nxz + (size_t)wid * 3;
    const float cx = C[0], cy = C[1], cz = C[2];
    const float r2 = (float)(0.2 * 0.2);
    int* G = gidx + (size_t)wid * KNB;
    int cnt = 0, first = 0;
    bool found = false;
    for (int j0 = 0; j0 < N1 && cnt < KNB; j0 += 64) {
        int j = j0 + lane;
        float d2 = sqdist(cx, cy, cz, X[j * 3 + 0], X[j * 3 + 1], X[j * 3 + 2]);
        bool hit = d2 < r2;
        unsigned long long mask = __ballot(hit);
        if (!found && mask) { first = j0 + __builtin_ctzll(mask); found = true; }
        if (hit) {
            int pos = cnt + __popcll(mask & ((1ull << lane) - 1ull));
            if (pos < KNB) G[pos] = j;
        }
        cnt += __popcll(mask);
    }
    if (cnt < KNB) {
        int pad = found ? first : 0;
        if (lane >= cnt && lane < KNB) G[lane] = pad;
    }
}

// ---------------- Ball query 2 (wave-per-center): 256 pts, r=0.4 ----------
__global__ __launch_bounds__(256) void ballq2_kernel(const float* __restrict__ xyz1,
                                                     const float* __restrict__ nxz2,
                                                     int* __restrict__ gidx) {
    const int wid = (blockIdx.x * 256 + threadIdx.x) >> 6;
    const int lane = threadIdx.x & 63;
    const int b = wid >> 7;
    const float* X = xyz1 + (size_t)b * (S1 * 3);
    const float* C = nxz2 + (size_t)wid * 3;
    const float cx = C[0], cy = C[1], cz = C[2];
    const float r2 = (float)(0.4 * 0.4);
    int* G = gidx + (size_t)wid * KNB;
    int cnt = 0, first = 0;
    bool found = false;
    for (int j0 = 0; j0 < S1 && cnt < KNB; j0 += 64) {
        int j = j0 + lane;
        float d2 = sqdist(cx, cy, cz, X[j * 3 + 0], X[j * 3 + 1], X[j * 3 + 2]);
        bool hit = d2 < r2;
        unsigned long long mask = __ballot(hit);
        if (!found && mask) { first = j0 + __builtin_ctzll(mask); found = true; }
        if (hit) {
            int pos = cnt + __popcll(mask & ((1ull << lane) - 1ull));
            if (pos < KNB) G[pos] = j;
        }
        cnt += __popcll(mask);
    }
    if (cnt < KNB) {
        int pad = found ? first : 0;
        if (lane >= cnt && lane < KNB) G[lane] = pad;
    }
}

// ---------------- Weight conversion: fp32 -> bf16 arena, K padded to x64 ----------------
//  w11b@0      64x64   | w12b@4096  128x64 | w20p@12288 128x192 (PERM: feat-first)
//  w21b@36864  128x128 | w22b@53248 256x128| w30p@86016 256x320 (PERM: feat-first)
//  w31b@167936 512x256 | w32b@299008 1024x512  total 823296
__global__ __launch_bounds__(256) void wconv_kernel(
    const float* __restrict__ w11, const float* __restrict__ w12,
    const float* __restrict__ w20, const float* __restrict__ w21,
    const float* __restrict__ w22, const float* __restrict__ w30,
    const float* __restrict__ w31, const float* __restrict__ w32,
    unsigned short* __restrict__ wb) {
    int u = blockIdx.x * 256 + threadIdx.x;
    if (u >= 823296) return;
    const float* src; int base, Kp, Ko; int perm = 0;   // perm: feature-count for feat-first layout
    if      (u < 4096)   { src = w11; base = 0;      Kp = 64;  Ko = 64;  }
    else if (u < 12288)  { src = w12; base = 4096;   Kp = 64;  Ko = 64;  }
    else if (u < 36864)  { src = w20; base = 12288;  Kp = 192; Ko = 131; perm = 128; }
    else if (u < 53248)  { src = w21; base = 36864;  Kp = 128; Ko = 128; }
    else if (u < 86016)  { src = w22; base = 53248;  Kp = 128; Ko = 128; }
    else if (u < 167936) { src = w30; base = 86016;  Kp = 320; Ko = 259; perm = 256; }
    else if (u < 299008) { src = w31; base = 167936; Kp = 256; Ko = 256; }
    else                 { src = w32; base = 299008; Kp = 512; Ko = 512; }
    int local = u - base;
    int n = local / Kp, k = local - n * Kp;
    float v;
    if (perm) {
        int ksrc = (k < perm) ? (k + 3) : ((k < perm + 3) ? (k - perm) : -1);
        v = (ksrc >= 0) ? src[(size_t)n * Ko + ksrc] : 0.f;
    } else {
        v = (k < Ko) ? src[(size_t)n * Ko + k] : 0.f;
    }
    wb[u] = f2bf(v);
}

// ---------------- Module 1 fused: gather + L0(K=3, VALU) + L1 + L2 MFMA + pool ---------
__global__ __launch_bounds__(256) void m1_kernel(
    const float* __restrict__ xyz, const float* __restrict__ nxz,
    const int* __restrict__ g1,
    const float* __restrict__ w10, const float* __restrict__ b10,
    const unsigned short* __restrict__ w11b, const float* __restrict__ b11,
    const unsigned short* __restrict__ w12b, const float* __restrict__ b12,
    unsigned short* __restrict__ f1) {
    constexpr int AP = 72;
    __shared__ __align__(16) unsigned short As[128 * AP];
    __shared__ __align__(16) unsigned short Hs[128 * AP];
    __shared__ __align__(16) unsigned short Bs[128 * AP];
    __shared__ float sxyz[128 * 3];
    const int t = threadIdx.x;
    const int lane = t & 63, w = t >> 6;
    const int r16 = lane & 15, q = lane >> 4;
    const int m0 = blockIdx.x * 128;

    if (t < 128) {
        int row = m0 + t, bs = row >> 5, b = bs >> 8, j = g1[row];
        const float* P = xyz + ((size_t)b * N1 + j) * 3;
        const float* Cc = nxz + (size_t)bs * 3;
        sxyz[t * 3 + 0] = P[0] - Cc[0];
        sxyz[t * 3 + 1] = P[1] - Cc[1];
        sxyz[t * 3 + 2] = P[2] - Cc[2];
    }
    for (int c = t; c < 64 * 8; c += 256) {
        int row = c >> 3, ch = c & 7;
        *(short8*)&Bs[row * AP + ch * 8] = *(const short8*)&w11b[row * 64 + ch * 8];
    }
    __syncthreads();
    {
        const int r = t >> 1, half = (t & 1) * 32;
        const float x = sxyz[r * 3 + 0], y = sxyz[r * 3 + 1], z = sxyz[r * 3 + 2];
        unsigned short tmp[32];
#pragma unroll
        for (int o = 0; o < 32; ++o) {
            int oo = half + o;
            float acc = b10[oo];
            acc = fmaf(x, w10[oo * 3 + 0], acc);
            acc = fmaf(y, w10[oo * 3 + 1], acc);
            acc = fmaf(z, w10[oo * 3 + 2], acc);
            tmp[o] = f2bf(fmaxf(acc, 0.f));
        }
#pragma unroll
        for (int c2 = 0; c2 < 4; ++c2)
            *(short8*)&As[r * AP + half + c2 * 8] = *(short8*)&tmp[c2 * 8];
    }
    __syncthreads();
    {
        f32x4 acc[2][4];
#pragma unroll
        for (int i = 0; i < 2; ++i)
#pragma unroll
            for (int j = 0; j < 4; ++j) acc[i][j] = (f32x4){0.f, 0.f, 0.f, 0.f};
#pragma unroll
        for (int kk = 0; kk < 64; kk += 32) {
            short8 a0 = *(const short8*)&As[(w * 32 + r16) * AP + kk + q * 8];
            short8 a1 = *(const short8*)&As[(w * 32 + 16 + r16) * AP + kk + q * 8];
#pragma unroll
            for (int j = 0; j < 4; ++j) {
                short8 bf = *(const short8*)&Bs[(j * 16 + r16) * AP + kk + q * 8];
                acc[0][j] = __builtin_amdgcn_mfma_f32_16x16x32_bf16(a0, bf, acc[0][j], 0, 0, 0);
                acc[1][j] = __builtin_amdgcn_mfma_f32_16x16x32_bf16(a1, bf, acc[1][j], 0, 0, 0);
            }
        }
#pragma unroll
        for (int i = 0; i < 2; ++i)
#pragma unroll
            for (int j = 0; j < 4; ++j) {
                int col = j * 16 + r16;
                float bv = b11[col];
#pragma unroll
                for (int r = 0; r < 4; ++r) {
                    int row = w * 32 + i * 16 + q * 4 + r;
                    Hs[row * AP + col] = f2bf(fmaxf(acc[i][j][r] + bv, 0.f));
                }
            }
    }
    __syncthreads();
    for (int c = t; c < 128 * 8; c += 256) {
        int row = c >> 3, ch = c & 7;
        *(short8*)&Bs[row * AP + ch * 8] = *(const short8*)&w12b[row * 64 + ch * 8];
    }
    __syncthreads();
    {
        f32x4 acc[2][8];
#pragma unroll
        for (int i = 0; i < 2; ++i)
#pragma unroll
            for (int j = 0; j < 8; ++j) acc[i][j] = (f32x4){0.f, 0.f, 0.f, 0.f};
#pragma unroll
        for (int kk = 0; kk < 64; kk += 32) {
            short8 a0 = *(const short8*)&Hs[(w * 32 + r16) * AP + kk + q * 8];
            short8 a1 = *(const short8*)&Hs[(w * 32 + 16 + r16) * AP + kk + q * 8];
#pragma unroll
            for (int j = 0; j < 8; ++j) {
                short8 bf = *(const short8*)&Bs[(j * 16 + r16) * AP + kk + q * 8];
                acc[0][j] = __builtin_amdgcn_mfma_f32_16x16x32_bf16(a0, bf, acc[0][j], 0, 0, 0);
                acc[1][j] = __builtin_amdgcn_mfma_f32_16x16x32_bf16(a1, bf, acc[1][j], 0, 0, 0);
            }
        }
#pragma unroll
        for (int j = 0; j < 8; ++j) {
            int col = j * 16 + r16;
            float bv = b12[col];
            float mv = 0.f;
#pragma unroll
            for (int i = 0; i < 2; ++i)
#pragma unroll
                for (int r = 0; r < 4; ++r)
                    mv = fmaxf(mv, acc[i][j][r] + bv);
            mv = fmaxf(mv, __shfl_xor(mv, 16));
            mv = fmaxf(mv, __shfl_xor(mv, 32));
            if (q == 0)
                f1[(size_t)((m0 >> 5) + w) * 128 + col] = f2bf(mv);
        }
    }
}

// ---------------- Module 2 fully fused: gather + L0(192) + L1(128) + L2(256)+pool ----
__global__ __launch_bounds__(256) void m2_kernel(
    const float* __restrict__ xyz1, const float* __restrict__ nxz2,
    const int* __restrict__ g2, const unsigned short* __restrict__ f1,
    const unsigned short* __restrict__ w20p, const float* __restrict__ b20,
    const unsigned short* __restrict__ w21b, const float* __restrict__ b21,
    const unsigned short* __restrict__ w22b, const float* __restrict__ b22,
    unsigned short* __restrict__ f2) {
    constexpr int AP = 72, HP = 136;
    __shared__ __align__(16) unsigned short smem[36864];   // 72 KB
    unsigned short* R1 = smem;
    unsigned short* R2 = smem + 18432;
    unsigned short* As = R1;
    unsigned short* Bs = R1 + 9216;
    unsigned short* H1 = R2;
    unsigned short* H2 = R1;
    unsigned short* Bs2 = R2;
    __shared__ int ribase[128];
    __shared__ unsigned short sxb[128 * 3];
    const int t = threadIdx.x;
    const int lane = t & 63, w = t >> 6;
    const int r16 = lane & 15, q = lane >> 4;
    const int m0 = blockIdx.x * 128;

    if (t < 128) {
        int row = m0 + t, bs = row >> 5, b = bs >> 7, j = g2[row];
        ribase[t] = (b * 256 + j) * 128;
        const float* P = xyz1 + ((size_t)b * S1 + j) * 3;
        const float* Cc = nxz2 + (size_t)bs * 3;
        sxb[t * 3 + 0] = f2bf(P[0] - Cc[0]);
        sxb[t * 3 + 1] = f2bf(P[1] - Cc[1]);
        sxb[t * 3 + 2] = f2bf(P[2] - Cc[2]);
    }
    __syncthreads();

    // ---- L0: K=192 (3 tiles), N=128 ----
    f32x4 acc[2][8];
#pragma unroll
    for (int i = 0; i < 2; ++i)
#pragma unroll
        for (int j = 0; j < 8; ++j) acc[i][j] = (f32x4){0.f, 0.f, 0.f, 0.f};
    for (int kt = 0; kt < 3; ++kt) {
        const int k0 = kt * 64;
        if (kt < 2) {
            for (int c = t; c < 128 * 8; c += 256) {
                int row = c >> 3, ch = c & 7;
                *(short8*)&As[row * AP + ch * 8] =
                    *(const short8*)&f1[(size_t)ribase[row] + k0 + ch * 8];
            }
        } else {
            for (int c = t; c < 128 * 8; c += 256) {
                int row = c >> 3, ch = c & 7;
                short8 v = (short8){0, 0, 0, 0, 0, 0, 0, 0};
                if (ch == 0) {
                    v[0] = (short)sxb[row * 3 + 0];
                    v[1] = (short)sxb[row * 3 + 1];
                    v[2] = (short)sxb[row * 3 + 2];
                }
                *(short8*)&As[row * AP + ch * 8] = v;
            }
        }
        for (int c = t; c < 128 * 8; c += 256) {
            int row = c >> 3, ch = c & 7;
            *(short8*)&Bs[row * AP + ch * 8] =
                *(const short8*)&w20p[(size_t)row * 192 + k0 + ch * 8];
        }
        __syncthreads();
#pragma unroll
        for (int kk = 0; kk < 64; kk += 32) {
            short8 a0 = *(const short8*)&As[(w * 32 + r16) * AP + kk + q * 8];
            short8 a1 = *(const short8*)&As[(w * 32 + 16 + r16) * AP + kk + q * 8];
#pragma unroll
            for (int j = 0; j < 8; ++j) {
                short8 bf = *(const short8*)&Bs[(j * 16 + r16) * AP + kk + q * 8];
                acc[0][j] = __builtin_amdgcn_mfma_f32_16x16x32_bf16(a0, bf, acc[0][j], 0, 0, 0);
                acc[1][j] = __builtin_amdgcn_mfma_f32_16x16x32_bf16(a1, bf, acc[1][j], 0, 0, 0);
            }
        }
        __syncthreads();
    }
#pragma unroll
    for (int i = 0; i < 2; ++i)
#pragma unroll
        for (int j = 0; j < 8; ++j) {
            int col = j * 16 + r16;
            float bv = b20[col];
#pragma unroll
            for (int r = 0; r < 4; ++r) {
                int row = w * 32 + i * 16 + q * 4 + r;
                H1[row * HP + col] = f2bf(fmaxf(acc[i][j][r] + bv, 0.f));
            }
        }
    __syncthreads();

    // ---- L1: K=128 (2 tiles), N=128 ----
#pragma unroll
    for (int i = 0; i < 2; ++i)
#pragma unroll
        for (int j = 0; j < 8; ++j) acc[i][j] = (f32x4){0.f, 0.f, 0.f, 0.f};
    for (int kt = 0; kt < 2; ++kt) {
        const int k0 = kt * 64;
        for (int c = t; c < 128 * 8; c += 256) {
            int row = c >> 3, ch = c & 7;
            *(short8*)&As[row * AP + ch * 8] =
                *(const short8*)&w21b[(size_t)row * 128 + k0 + ch * 8];
        }
        __syncthreads();
#pragma unroll
        for (int kk = 0; kk < 64; kk += 32) {
            short8 a0 = *(const short8*)&H1[(w * 32 + r16) * HP + k0 + kk + q * 8];
            short8 a1 = *(const short8*)&H1[(w * 32 + 16 + r16) * HP + k0 + kk + q * 8];
#pragma unroll
            for (int j = 0; j < 8; ++j) {
                short8 bf = *(const short8*)&As[(j * 16 + r16) * AP + kk + q * 8];
                acc[0][j] = __builtin_amdgcn_mfma_f32_16x16x32_bf16(a0, bf, acc[0][j], 0, 0, 0);
                acc[1][j] = __builtin_amdgcn_mfma_f32_16x16x32_bf16(a1, bf, acc[1][j], 0, 0, 0);
            }
        }
        __syncthreads();
    }
#pragma unroll
    for (int i = 0; i < 2; ++i)
#pragma unroll
        for (int j = 0; j < 8; ++j) {
            int col = j * 16 + r16;
            float bv = b21[col];
#pragma unroll
            for (int r = 0; r < 4; ++r) {
                int row = w * 32 + i * 16 + q * 4 + r;
                H2[row * HP + col] = f2bf(fmaxf(acc[i][j][r] + bv, 0.f));
            }
        }
    __syncthreads();

    // ---- L2: K=128 (2 tiles), N=256 + pool ----
    f32x4 acc2[2][16];
#pragma unroll
    for (int i = 0; i < 2; ++i)
#pragma unroll
        for (int j = 0; j < 16; ++j) acc2[i][j] = (f32x4){0.f, 0.f, 0.f, 0.f};
    for (int kt = 0; kt < 2; ++kt) {
        const int k0 = kt * 64;
        for (int c = t; c < 256 * 8; c += 256) {
            int row = c >> 3, ch = c & 7;
            *(short8*)&Bs2[row * AP + ch * 8] =
                *(const short8*)&w22b[(size_t)row * 128 + k0 + ch * 8];
        }
        __syncthreads();
#pragma unroll
        for (int kk = 0; kk < 64; kk += 32) {
            short8 a0 = *(const short8*)&H2[(w * 32 + r16) * HP + k0 + kk + q * 8];
            short8 a1 = *(const short8*)&H2[(w * 32 + 16 + r16) * HP + k0 + kk + q * 8];
#pragma unroll
            for (int j = 0; j < 16; ++j) {
                short8 bf = *(const short8*)&Bs2[(j * 16 + r16) * AP + kk + q * 8];
                acc2[0][j] = __builtin_amdgcn_mfma_f32_16x16x32_bf16(a0, bf, acc2[0][j], 0, 0, 0);
                acc2[1][j] = __builtin_amdgcn_mfma_f32_16x16x32_bf16(a1, bf, acc2[1][j], 0, 0, 0);
            }
        }
        __syncthreads();
    }
#pragma unroll
    for (int j = 0; j < 16; ++j) {
        int col = j * 16 + r16;
        float bv = b22[col];
        float mv = 0.f;
#pragma unroll
        for (int i = 0; i < 2; ++i)
#pragma unroll
            for (int r = 0; r < 4; ++r)
                mv = fmaxf(mv, acc2[i][j][r] + bv);
        mv = fmaxf(mv, __shfl_xor(mv, 16));
        mv = fmaxf(mv, __shfl_xor(mv, 32));
        if (q == 0)
            f2[(size_t)((m0 >> 5) + w) * 256 + col] = f2bf(mv);
    }
}

// ---------------- Module 3 layer 0 with fused concat (feat-first K=320) ---------------
__global__ __launch_bounds__(256) void l30_kernel(
    const float* __restrict__ nxz2, const unsigned short* __restrict__ f2,
    const unsigned short* __restrict__ w30p, const float* __restrict__ bias,
    unsigned short* __restrict__ C) {
    constexpr int AP = 72;
    __shared__ __align__(16) unsigned short As[128 * AP];
    __shared__ __align__(16) unsigned short Bs[128 * AP];
    const int t = threadIdx.x;
    const int lane = t & 63, w = t >> 6;
    const int r16 = lane & 15, q = lane >> 4;
    const int m0 = blockIdx.x * 128;
    const int n0 = blockIdx.y * 128;

    f32x4 acc[2][8];
#pragma unroll
    for (int i = 0; i < 2; ++i)
#pragma unroll
        for (int j = 0; j < 8; ++j) acc[i][j] = (f32x4){0.f, 0.f, 0.f, 0.f};

    for (int kt = 0; kt < 5; ++kt) {
        const int k0 = kt * 64;
        if (kt < 4) {
            for (int c = t; c < 128 * 8; c += 256) {
                int row = c >> 3, ch = c & 7;
                *(short8*)&As[row * AP + ch * 8] =
                    *(const short8*)&f2[(size_t)(m0 + row) * 256 + k0 + ch * 8];
            }
        } else {
            for (int c = t; c < 128 * 8; c += 256) {
                int row = c >> 3, ch = c & 7;
                short8 v = (short8){0, 0, 0, 0, 0, 0, 0, 0};
                if (ch == 0) {
                    const float* P = nxz2 + (size_t)(m0 + row) * 3;
                    v[0] = (short)f2bf(P[0]);
                    v[1] = (short)f2bf(P[1]);
                    v[2] = (short)f2bf(P[2]);
                }
                *(short8*)&As[row * AP + ch * 8] = v;
            }
        }
        for (int c = t; c < 128 * 8; c += 256) {
            int row = c >> 3, ch = c & 7;
            *(short8*)&Bs[row * AP + ch * 8] =
                *(const short8*)&w30p[(size_t)(n0 + row) * 320 + k0 + ch * 8];
        }
        __syncthreads();
#pragma unroll
        for (int kk = 0; kk < 64; kk += 32) {
            short8 a0 = *(const short8*)&As[(w * 32 + r16) * AP + kk + q * 8];
            short8 a1 = *(const short8*)&As[(w * 32 + 16 + r16) * AP + kk + q * 8];
#pragma unroll
            for (int j = 0; j < 8; ++j) {
                short8 bf = *(const short8*)&Bs[(j * 16 + r16) * AP + kk + q * 8];
                acc[0][j] = __builtin_amdgcn_mfma_f32_16x16x32_bf16(a0, bf, acc[0][j], 0, 0, 0);
                acc[1][j] = __builtin_amdgcn_mfma_f32_16x16x32_bf16(a1, bf, acc[1][j], 0, 0, 0);
            }
        }
        __syncthreads();
    }
#pragma unroll
    for (int i = 0; i < 2; ++i)
#pragma unroll
        for (int j = 0; j < 8; ++j) {
            int col = n0 + j * 16 + r16;
            float bv = bias[col];
#pragma unroll
            for (int r = 0; r < 4; ++r) {
                int row = m0 + w * 32 + i * 16 + q * 4 + r;
                C[(size_t)row * 256 + col] = f2bf(fmaxf(acc[i][j][r] + bv, 0.f));
            }
        }
}

// ---------------- bf16 MFMA GEMM (BM templated): C = relu(X*W^T + bias), BN=128 --------
template <int BM_>
__global__ __launch_bounds__(256) void mfma_gemm(const unsigned short* __restrict__ X,
                                                 const unsigned short* __restrict__ W,
                                                 const float* __restrict__ bias,
                                                 unsigned short* __restrict__ C,
                                                 int M, int N, int K) {
    constexpr int BK = 64, AP = BK + 8;
    constexpr int RW = BM_ / 64;         // M-frags per wave
    constexpr int WR = BM_ / 4;          // rows per wave
    __shared__ __align__(16) unsigned short As[BM_ * AP];
    __shared__ __align__(16) unsigned short Bs[128 * AP];
    const int t = threadIdx.x;
    const int lane = t & 63, w = t >> 6;
    const int m0 = blockIdx.x * BM_;
    const int n0 = blockIdx.y * 128;
    const int r16 = lane & 15, q = lane >> 4;

    f32x4 acc[RW][8];
#pragma unroll
    for (int i = 0; i < RW; ++i)
#pragma unroll
        for (int j = 0; j < 8; ++j) acc[i][j] = (f32x4){0.f, 0.f, 0.f, 0.f};

    for (int k0 = 0; k0 < K; k0 += BK) {
        for (int c = t; c < BM_ * 8; c += 256) {
            int row = c >> 3, ch = c & 7;
            *(short8*)&As[row * AP + ch * 8] =
                *(const short8*)&X[(size_t)(m0 + row) * K + k0 + ch * 8];
        }
        for (int c = t; c < 128 * 8; c += 256) {
            int row = c >> 3, ch = c & 7;
            *(short8*)&Bs[row * AP + ch * 8] =
                *(const short8*)&W[(size_t)(n0 + row) * K + k0 + ch * 8];
        }
        __syncthreads();
#pragma unroll
        for (int kk = 0; kk < BK; kk += 32) {
            short8 a[RW];
#pragma unroll
            for (int i = 0; i < RW; ++i)
                a[i] = *(const short8*)&As[(w * WR + i * 16 + r16) * AP + kk + q * 8];
#pragma unroll
            for (int j = 0; j < 8; ++j) {
                short8 bf = *(const short8*)&Bs[(j * 16 + r16) * AP + kk + q * 8];
#pragma unroll
                for (int i = 0; i < RW; ++i)
                    acc[i][j] = __builtin_amdgcn_mfma_f32_16x16x32_bf16(a[i], bf, acc[i][j], 0, 0, 0);
            }
        }
        __syncthreads();
    }
#pragma unroll
    for (int i = 0; i < RW; ++i)
#pragma unroll
        for (int j = 0; j < 8; ++j) {
            int col = n0 + j * 16 + r16;
            float bv = bias[col];
#pragma unroll
            for (int r = 0; r < 4; ++r) {
                int row = m0 + w * WR + i * 16 + q * 4 + r;
                C[(size_t)row * N + col] = f2bf(fmaxf(acc[i][j][r] + bv, 0.f));
            }
        }
}

// ---------------- Final GEMM (N=1024, K=512) + max over 128 rows -> fp32 out ----------
// BM=128 = one batch per block-row; pooled output out[batch][n0+col].
__global__ __launch_bounds__(256) void gemm_pool128(const unsigned short* __restrict__ X,
                                                    const unsigned short* __restrict__ W,
                                                    const float* __restrict__ bias,
                                                    float* __restrict__ out) {
    constexpr int BK = 64, AP = BK + 8, K = 512;
    __shared__ __align__(16) unsigned short As[128 * AP];
    __shared__ __align__(16) unsigned short Bs[128 * AP];
    __shared__ float pool[4][128];
    const int t = threadIdx.x;
    const int lane = t & 63, w = t >> 6;
    const int m0 = blockIdx.x * 128;
    const int n0 = blockIdx.y * 128;
    const int r16 = lane & 15, q = lane >> 4;

    f32x4 acc[2][8];
#pragma unroll
    for (int i = 0; i < 2; ++i)
#pragma unroll
        for (int j = 0; j < 8; ++j) acc[i][j] = (f32x4){0.f, 0.f, 0.f, 0.f};

    for (int k0 = 0; k0 < K; k0 += BK) {
        for (int c = t; c < 128 * 8; c += 256) {
            int row = c >> 3, ch = c & 7;
            *(short8*)&As[row * AP + ch * 8] =
                *(const short8*)&X[(size_t)(m0 + row) * K + k0 + ch * 8];
        }
        for (int c = t; c < 128 * 8; c += 256) {
            int row = c >> 3, ch = c & 7;
            *(short8*)&Bs[row * AP + ch * 8] =
                *(const short8*)&W[(size_t)(n0 + row) * K + k0 + ch * 8];
        }
        __syncthreads();
#pragma unroll
        for (int kk = 0; kk < BK; kk += 32) {
            short8 a0 = *(const short8*)&As[(w * 32 + r16) * AP + kk + q * 8];
            short8 a1 = *(const short8*)&As[(w * 32 + 16 + r16) * AP + kk + q * 8];
#pragma unroll
            for (int j = 0; j < 8; ++j) {
                short8 bf = *(const short8*)&Bs[(j * 16 + r16) * AP + kk + q * 8];
                acc[0][j] = __builtin_amdgcn_mfma_f32_16x16x32_bf16(a0, bf, acc[0][j], 0, 0, 0);
                acc[1][j] = __builtin_amdgcn_mfma_f32_16x16x32_bf16(a1, bf, acc[1][j], 0, 0, 0);
            }
        }
        __syncthreads();
    }
    // wave-level pool over its 32 rows (relu via 0-init), then cross-wave via LDS
#pragma unroll
    for (int j = 0; j < 8; ++j) {
        float bv = bias[n0 + j * 16 + r16];
        float mv = 0.f;
#pragma unroll
        for (int i = 0; i < 2; ++i)
#pragma unroll
            for (int r = 0; r < 4; ++r)
                mv = fmaxf(mv, acc[i][j][r] + bv);
        mv = fmaxf(mv, __shfl_xor(mv, 16));
        mv = fmaxf(mv, __shfl_xor(mv, 32));
        if (q == 0) pool[w][j * 16 + r16] = mv;
    }
    __syncthreads();
    if (t < 128) {
        float m = fmaxf(fmaxf(pool[0][t], pool[1][t]), fmaxf(pool[2][t], pool[3][t]));
        out[(size_t)blockIdx.x * 1024 + n0 + t] = m;
    }
}

extern "C" void kernel_launch(void* const* d_in, const int* in_sizes, int n_in,
                              void* d_out, int out_size, void* d_ws, size_t ws_size,
                              hipStream_t stream) {
    const float* data = (const float*)d_in[0];
    const float* w10 = (const float*)d_in[1];  const float* b10 = (const float*)d_in[2];
    const float* w11 = (const float*)d_in[3];  const float* b11 = (const float*)d_in[4];
    const float* w12 = (const float*)d_in[5];  const float* b12 = (const float*)d_in[6];
    const float* w20 = (const float*)d_in[7];  const float* b20 = (const float*)d_in[8];
    const float* w21 = (const float*)d_in[9];  const float* b21 = (const float*)d_in[10];
    const float* w22 = (const float*)d_in[11]; const float* b22 = (const float*)d_in[12];
    const float* w30 = (const float*)d_in[13]; const float* b30 = (const float*)d_in[14];
    const float* w31 = (const float*)d_in[15]; const float* b31 = (const float*)d_in[16];
    const float* w32 = (const float*)d_in[17]; const float* b32 = (const float*)d_in[18];
    float* out = (float*)d_out;

    char* ws = (char*)d_ws;
    size_t off = 0;
    auto alloc = [&](size_t bytes) -> void* {
        void* p = ws + off;
        off += (bytes + 255) & ~(size_t)255;
        return p;
    };
    float* nxz1 = (float*)alloc((size_t)BT * S1 * 3 * 4);
    int*   g1   = (int*)  alloc((size_t)BT * S1 * KNB * 4);
    float* nxz2 = (float*)alloc((size_t)BT * S2 * 3 * 4);
    int*   g2   = (int*)  alloc((size_t)BT * S2 * KNB * 4);
    unsigned short* wb  = (unsigned short*)alloc((size_t)823296 * 2);
    unsigned short* f1  = (unsigned short*)alloc((size_t)8192 * 128 * 2);
    unsigned short* f2  = (unsigned short*)alloc((size_t)4096 * 256 * 2);
    unsigned short* C1  = (unsigned short*)alloc((size_t)4096 * 256 * 2);
    unsigned short* C2  = (unsigned short*)alloc((size_t)4096 * 512 * 2);

    const unsigned short* w11b = wb + 0;
    const unsigned short* w12b = wb + 4096;
    const unsigned short* w20p = wb + 12288;
    const unsigned short* w21b = wb + 36864;
    const unsigned short* w22b = wb + 53248;
    const unsigned short* w30p = wb + 86016;
    const unsigned short* w31b = wb + 167936;
    const unsigned short* w32b = wb + 299008;

    wconv_kernel<<<(823296 + 255) / 256, 256, 0, stream>>>(w11, w12, w20, w21, w22, w30, w31, w32, wb);

    // ---- module 1 ----
    fps1_kernel<<<BT, 256, 0, stream>>>(data, nxz1);
    ballq1_kernel<<<(BT * S1) / 4, 256, 0, stream>>>(data, nxz1, g1);
    m1_kernel<<<262144 / 128, 256, 0, stream>>>(data, nxz1, g1, w10, b10, w11b, b11, w12b, b12, f1);
    // ---- module 2 ----
    fps2_kernel<<<BT, 64, 0, stream>>>(nxz1, nxz2);
    ballq2_kernel<<<(BT * S2) / 4, 256, 0, stream>>>(nxz1, nxz2, g2);
    m2_kernel<<<131072 / 128, 256, 0, stream>>>(nxz1, nxz2, g2, f1, w20p, b20, w21b, b21, w22b, b22, f2);
    // ---- module 3 ----
    l30_kernel<<<dim3(4096 / 128, 2), 256, 0, stream>>>(nxz2, f2, w30p, b30, C1);
    mfma_gemm<64><<<dim3(4096 / 64, 4), 256, 0, stream>>>(C1, w31b, b31, C2, 4096, 512, 256);
    gemm_pool128<<<dim3(4096 / 128, 8), 256, 0, stream>>>(C2, w32b, b32, out);
}

// Round 12
// 485.607 us; speedup vs baseline: 1.1867x; 1.0010x over previous
//
#include <hip/hip_runtime.h>
#include <hip/hip_bf16.h>
#include <cstdint>
#include <cstddef>

// Problem constants: data (4,8,4096,3) -> 32 batches x 4096 points
#define BT 32
#define N1 4096
#define S1 256
#define S2 128
#define KNB 32

typedef __attribute__((ext_vector_type(8))) short short8;   // 8 bf16 in 4 VGPRs
typedef __attribute__((ext_vector_type(4))) float f32x4;

__device__ __forceinline__ float sqdist(float ax, float ay, float az,
                                        float bx, float by, float bz) {
    // exact replication of sum((a-b)**2, axis=-1): mul then left-to-right add, NO fma
    float dx = __fsub_rn(ax, bx), dy = __fsub_rn(ay, by), dz = __fsub_rn(az, bz);
    return __fadd_rn(__fadd_rn(__fmul_rn(dx, dx), __fmul_rn(dy, dy)), __fmul_rn(dz, dz));
}

// bf16 round-to-nearest-even (values here are finite)
__device__ __forceinline__ unsigned short f2bf(float f) {
    unsigned u = __float_as_uint(f);
    return (unsigned short)((u + 0x7FFFu + ((u >> 16) & 1u)) >> 16);
}
__device__ __forceinline__ float bf2f(unsigned short h) {
    return __uint_as_float(((unsigned)h) << 16);
}

// pack (value, index) for argmax-with-first-index-tie-break: distances >= 0 so float
// bits are monotonic as uint; on equal value, larger ~idx == smaller idx wins.
__device__ __forceinline__ unsigned long long packvi(float v, int idx) {
    return ((unsigned long long)__float_as_uint(v) << 32) | (unsigned)(~idx);
}

// DPP row-rotate max for u64 (rotate within 16-lane rows; commutative reduce)
template <int CTRL>
__device__ __forceinline__ unsigned long long dppmax(unsigned long long v) {
    int lo = (int)(unsigned)(v & 0xFFFFFFFFull);
    int hi = (int)(unsigned)(v >> 32);
    int lo2 = __builtin_amdgcn_update_dpp(0, lo, CTRL, 0xF, 0xF, false);
    int hi2 = __builtin_amdgcn_update_dpp(0, hi, CTRL, 0xF, 0xF, false);
    unsigned long long o = ((unsigned long long)(unsigned)hi2 << 32) | (unsigned)lo2;
    return o > v ? o : v;
}
#define ROR1 0x121
#define ROR2 0x122
#define ROR4 0x124
#define ROR8 0x128

// ---------------- FPS module 1: N=4096 -> 256, one block/batch, 256 threads ----------
// (R8/R9/R11-proven: 153us. Slot reduce + post-barrier s4[vi] coord read. DO NOT TOUCH:
// 512-thr, payload-DPP reduce, and coord-prefetch variants all measured equal or worse.)
__global__ __launch_bounds__(256) void fps1_kernel(const float* __restrict__ xyz,
                                                   float* __restrict__ nxz) {
    const int b = blockIdx.x, tid = threadIdx.x;
    const int lane = tid & 63, wv = tid >> 6;      // 4 waves
    const float* X = xyz + (size_t)b * (N1 * 3);
    __shared__ float4 s4[N1];                      // 64 KB
    __shared__ unsigned long long slots[2][16];
    __shared__ float hist[S1 * 3];
    float px[16], py[16], pz[16], md[16];
    int bidx[16];
#pragma unroll
    for (int j = 0; j < 16; ++j) {
        int i = tid + 256 * j;
        float x = X[i * 3 + 0], y = X[i * 3 + 1], z = X[i * 3 + 2];
        s4[i] = make_float4(x, y, z, 0.f);
        px[j] = x; py[j] = y; pz[j] = z;
        md[j] = 1e10f;
        bidx[j] = i;
    }
    if (tid == 0) { hist[0] = X[0]; hist[1] = X[1]; hist[2] = X[2]; }
    __syncthreads();
    float4 c0 = s4[0];
    float lx = c0.x, ly = c0.y, lz = c0.z;
    for (int t = 1; t < S1; ++t) {
        float bv = -1.0f; int bi = 0;
#pragma unroll
        for (int j = 0; j < 16; ++j) {
            float d = sqdist(px[j], py[j], pz[j], lx, ly, lz);
            float m = fminf(md[j], d);
            md[j] = m;
            if (m > bv) { bv = m; bi = bidx[j]; }   // ascending flat idx: first max kept
        }
        unsigned long long best = packvi(bv, bi);
        best = dppmax<ROR1>(best);
        best = dppmax<ROR2>(best);
        best = dppmax<ROR4>(best);
        best = dppmax<ROR8>(best);                  // row (16-lane) max
        if ((lane & 15) == 0) slots[t & 1][wv * 4 + (lane >> 4)] = best;
        __syncthreads();
        unsigned long long w = slots[t & 1][lane & 15];
        w = dppmax<ROR1>(w);
        w = dppmax<ROR2>(w);
        w = dppmax<ROR4>(w);
        w = dppmax<ROR8>(w);
        int vi = (int)(~(unsigned)w);
        float4 c = s4[vi];
        lx = c.x; ly = c.y; lz = c.z;
        if (tid == 0) { hist[t * 3 + 0] = lx; hist[t * 3 + 1] = ly; hist[t * 3 + 2] = lz; }
    }
    __syncthreads();
    for (int u = tid; u < S1 * 3; u += 256) nxz[(size_t)b * S1 * 3 + u] = hist[u];
}

// ---------------- FPS module 2: N=256 -> 128, ONE WAVE per batch ----------
__global__ __launch_bounds__(64) void fps2_kernel(const float* __restrict__ xyz1,
                                                  float* __restrict__ nxz2) {
    const int b = blockIdx.x, lane = threadIdx.x;
    const float* X = xyz1 + (size_t)b * (S1 * 3);
    __shared__ float4 s4[S1];
    float px[4], py[4], pz[4], md[4];
    int bidx[4];
#pragma unroll
    for (int j = 0; j < 4; ++j) {
        int i = lane + 64 * j;
        float x = X[i * 3 + 0], y = X[i * 3 + 1], z = X[i * 3 + 2];
        s4[i] = make_float4(x, y, z, 0.f);
        px[j] = x; py[j] = y; pz[j] = z;
        md[j] = 1e10f;
        bidx[j] = i;
    }
    if (lane == 0) {
        nxz2[(size_t)b * S2 * 3 + 0] = X[0];
        nxz2[(size_t)b * S2 * 3 + 1] = X[1];
        nxz2[(size_t)b * S2 * 3 + 2] = X[2];
    }
    // single wave: LDS writes above are wave-synchronous
    float4 cc = s4[0];
    float lx = cc.x, ly = cc.y, lz = cc.z;
    for (int t = 1; t < S2; ++t) {
        float bv = -1.0f; int bi = 0;
#pragma unroll
        for (int j = 0; j < 4; ++j) {
            float d = sqdist(px[j], py[j], pz[j], lx, ly, lz);
            float m = fminf(md[j], d);
            md[j] = m;
            if (m > bv) { bv = m; bi = bidx[j]; }
        }
        unsigned long long best = packvi(bv, bi);
        best = dppmax<ROR1>(best);
        best = dppmax<ROR2>(best);
        best = dppmax<ROR4>(best);
        best = dppmax<ROR8>(best);
        { unsigned long long o = __shfl_xor(best, 16); best = o > best ? o : best; }
        { unsigned long long o = __shfl_xor(best, 32); best = o > best ? o : best; }
        int vi = (int)(~(unsigned)best);
        float4 c = s4[vi];
        lx = c.x; ly = c.y; lz = c.z;
        if (lane == 0) {
            float* dst = nxz2 + ((size_t)b * S2 + t) * 3;
            dst[0] = lx; dst[1] = ly; dst[2] = lz;
        }
    }
}

// ---------------- Ball query 1 (wave-per-center): 4096 pts, r=0.2 ----------
__global__ __launch_bounds__(256) void ballq1_kernel(const float* __restrict__ xyz,
                                                     const float* __restrict__ nxz,
                                                     int* __restrict__ gidx) {
    const int wid = (blockIdx.x * 256 + threadIdx.x) >> 6;
    const int lane = threadIdx.x & 63;
    const int b = wid >> 8;
    const float* X = xyz + (size_t)b * (N1 * 3);
    const float* C = nxz + (size_t)wid * 3;
    const float cx = C[0], cy = C[1], cz = C[2];
    const float r2 = (float)(0.2 * 0.2);
    int* G = gidx + (size_t)wid * KNB;
    int cnt = 0, first = 0;
    bool found = false;
    for (int j0 = 0; j0 < N1 && cnt < KNB; j0 += 64) {
        int j = j0 + lane;
        float d2 = sqdist(cx, cy, cz, X[j * 3 + 0], X[j * 3 + 1], X[j * 3 + 2]);
        bool hit = d2 < r2;
        unsigned long long mask = __ballot(hit);
        if (!found && mask) { first = j0 + __builtin_ctzll(mask); found = true; }
        if (hit) {
            int pos = cnt + __popcll(mask & ((1ull << lane) - 1ull));
            if (pos < KNB) G[pos] = j;
        }
        cnt += __popcll(mask);
    }
    if (cnt < KNB) {
        int pad = found ? first : 0;
        if (lane >= cnt && lane < KNB) G[lane] = pad;
    }
}

// ---------------- Ball query 2 (wave-per-center): 256 pts, r=0.4 ----------
__global__ __launch_bounds__(256) void ballq2_kernel(const float* __restrict__ xyz1,
                                                     const float* __restrict__ nxz2,
                                                     int* __restrict__ gidx) {
    const int wid = (blockIdx.x * 256 + threadIdx.x) >> 6;
    const int lane = threadIdx.x & 63;
    const int b = wid >> 7;
    const float* X = xyz1 + (size_t)b * (S1 * 3);
    const float* C = nxz2 + (size_t)wid * 3;
    const float cx = C[0], cy = C[1], cz = C[2];
    const float r2 = (float)(0.4 * 0.4);
    int* G = gidx + (size_t)wid * KNB;
    int cnt = 0, first = 0;
    bool found = false;
    for (int j0 = 0; j0 < S1 && cnt < KNB; j0 += 64) {
        int j = j0 + lane;
        float d2 = sqdist(cx, cy, cz, X[j * 3 + 0], X[j * 3 + 1], X[j * 3 + 2]);
        bool hit = d2 < r2;
        unsigned long long mask = __ballot(hit);
        if (!found && mask) { first = j0 + __builtin_ctzll(mask); found = true; }
        if (hit) {
            int pos = cnt + __popcll(mask & ((1ull << lane) - 1ull));
            if (pos < KNB) G[pos] = j;
        }
        cnt += __popcll(mask);
    }
    if (cnt < KNB) {
        int pad = found ? first : 0;
        if (lane >= cnt && lane < KNB) G[lane] = pad;
    }
}

// ---------------- Weight conversion: fp32 -> bf16 arena, K padded to x64 ----------------
//  w11b@0      64x64   | w12b@4096  128x64 | w20p@12288 128x192 (PERM: feat-first)
//  w21b@36864  128x128 | w22b@53248 256x128| w30p@86016 256x320 (PERM: feat-first)
//  w31b@167936 512x256 | w32b@299008 1024x512  total 823296
__global__ __launch_bounds__(256) void wconv_kernel(
    const float* __restrict__ w11, const float* __restrict__ w12,
    const float* __restrict__ w20, const float* __restrict__ w21,
    const float* __restrict__ w22, const float* __restrict__ w30,
    const float* __restrict__ w31, const float* __restrict__ w32,
    unsigned short* __restrict__ wb) {
    int u = blockIdx.x * 256 + threadIdx.x;
    if (u >= 823296) return;
    const float* src; int base, Kp, Ko; int perm = 0;   // perm: feature-count for feat-first layout
    if      (u < 4096)   { src = w11; base = 0;      Kp = 64;  Ko = 64;  }
    else if (u < 12288)  { src = w12; base = 4096;   Kp = 64;  Ko = 64;  }
    else if (u < 36864)  { src = w20; base = 12288;  Kp = 192; Ko = 131; perm = 128; }
    else if (u < 53248)  { src = w21; base = 36864;  Kp = 128; Ko = 128; }
    else if (u < 86016)  { src = w22; base = 53248;  Kp = 128; Ko = 128; }
    else if (u < 167936) { src = w30; base = 86016;  Kp = 320; Ko = 259; perm = 256; }
    else if (u < 299008) { src = w31; base = 167936; Kp = 256; Ko = 256; }
    else                 { src = w32; base = 299008; Kp = 512; Ko = 512; }
    int local = u - base;
    int n = local / Kp, k = local - n * Kp;
    float v;
    if (perm) {
        int ksrc = (k < perm) ? (k + 3) : ((k < perm + 3) ? (k - perm) : -1);
        v = (ksrc >= 0) ? src[(size_t)n * Ko + ksrc] : 0.f;
    } else {
        v = (k < Ko) ? src[(size_t)n * Ko + k] : 0.f;
    }
    wb[u] = f2bf(v);
}

// ---------------- Module 1 fused: gather + L0(K=3, VALU) + L1 + L2 MFMA + pool ---------
// R12: w11 AND w12 staged together at start (Bs rows 0..63 = w11, rows 64..191 = w12),
// removing the mid-kernel restage loop + one barrier per block.
__global__ __launch_bounds__(256) void m1_kernel(
    const float* __restrict__ xyz, const float* __restrict__ nxz,
    const int* __restrict__ g1,
    const float* __restrict__ w10, const float* __restrict__ b10,
    const unsigned short* __restrict__ w11b, const float* __restrict__ b11,
    const unsigned short* __restrict__ w12b, const float* __restrict__ b12,
    unsigned short* __restrict__ f1) {
    constexpr int AP = 72;
    __shared__ __align__(16) unsigned short As[128 * AP];
    __shared__ __align__(16) unsigned short Hs[128 * AP];
    __shared__ __align__(16) unsigned short Bs[192 * AP];   // w11 (64 rows) + w12 (128 rows)
    __shared__ float sxyz[128 * 3];
    const int t = threadIdx.x;
    const int lane = t & 63, w = t >> 6;
    const int r16 = lane & 15, q = lane >> 4;
    const int m0 = blockIdx.x * 128;

    if (t < 128) {
        int row = m0 + t, bs = row >> 5, b = bs >> 8, j = g1[row];
        const float* P = xyz + ((size_t)b * N1 + j) * 3;
        const float* Cc = nxz + (size_t)bs * 3;
        sxyz[t * 3 + 0] = P[0] - Cc[0];
        sxyz[t * 3 + 1] = P[1] - Cc[1];
        sxyz[t * 3 + 2] = P[2] - Cc[2];
    }
    // stage w11 (rows 0..63) and w12 (rows 64..191) in one pass
    for (int c = t; c < 192 * 8; c += 256) {
        int row = c >> 3, ch = c & 7;
        const unsigned short* src = (row < 64) ? &w11b[row * 64 + ch * 8]
                                               : &w12b[(row - 64) * 64 + ch * 8];
        *(short8*)&Bs[row * AP + ch * 8] = *(const short8*)src;
    }
    __syncthreads();
    {
        const int r = t >> 1, half = (t & 1) * 32;
        const float x = sxyz[r * 3 + 0], y = sxyz[r * 3 + 1], z = sxyz[r * 3 + 2];
        unsigned short tmp[32];
#pragma unroll
        for (int o = 0; o < 32; ++o) {
            int oo = half + o;
            float acc = b10[oo];
            acc = fmaf(x, w10[oo * 3 + 0], acc);
            acc = fmaf(y, w10[oo * 3 + 1], acc);
            acc = fmaf(z, w10[oo * 3 + 2], acc);
            tmp[o] = f2bf(fmaxf(acc, 0.f));
        }
#pragma unroll
        for (int c2 = 0; c2 < 4; ++c2)
            *(short8*)&As[r * AP + half + c2 * 8] = *(short8*)&tmp[c2 * 8];
    }
    __syncthreads();
    {
        f32x4 acc[2][4];
#pragma unroll
        for (int i = 0; i < 2; ++i)
#pragma unroll
            for (int j = 0; j < 4; ++j) acc[i][j] = (f32x4){0.f, 0.f, 0.f, 0.f};
#pragma unroll
        for (int kk = 0; kk < 64; kk += 32) {
            short8 a0 = *(const short8*)&As[(w * 32 + r16) * AP + kk + q * 8];
            short8 a1 = *(const short8*)&As[(w * 32 + 16 + r16) * AP + kk + q * 8];
#pragma unroll
            for (int j = 0; j < 4; ++j) {
                short8 bf = *(const short8*)&Bs[(j * 16 + r16) * AP + kk + q * 8];
                acc[0][j] = __builtin_amdgcn_mfma_f32_16x16x32_bf16(a0, bf, acc[0][j], 0, 0, 0);
                acc[1][j] = __builtin_amdgcn_mfma_f32_16x16x32_bf16(a1, bf, acc[1][j], 0, 0, 0);
            }
        }
#pragma unroll
        for (int i = 0; i < 2; ++i)
#pragma unroll
            for (int j = 0; j < 4; ++j) {
                int col = j * 16 + r16;
                float bv = b11[col];
#pragma unroll
                for (int r = 0; r < 4; ++r) {
                    int row = w * 32 + i * 16 + q * 4 + r;
                    Hs[row * AP + col] = f2bf(fmaxf(acc[i][j][r] + bv, 0.f));
                }
            }
    }
    __syncthreads();   // Hs fully written; Bs rows 64.. already hold w12
    {
        f32x4 acc[2][8];
#pragma unroll
        for (int i = 0; i < 2; ++i)
#pragma unroll
            for (int j = 0; j < 8; ++j) acc[i][j] = (f32x4){0.f, 0.f, 0.f, 0.f};
#pragma unroll
        for (int kk = 0; kk < 64; kk += 32) {
            short8 a0 = *(const short8*)&Hs[(w * 32 + r16) * AP + kk + q * 8];
            short8 a1 = *(const short8*)&Hs[(w * 32 + 16 + r16) * AP + kk + q * 8];
#pragma unroll
            for (int j = 0; j < 8; ++j) {
                short8 bf = *(const short8*)&Bs[(64 + j * 16 + r16) * AP + kk + q * 8];
                acc[0][j] = __builtin_amdgcn_mfma_f32_16x16x32_bf16(a0, bf, acc[0][j], 0, 0, 0);
                acc[1][j] = __builtin_amdgcn_mfma_f32_16x16x32_bf16(a1, bf, acc[1][j], 0, 0, 0);
            }
        }
#pragma unroll
        for (int j = 0; j < 8; ++j) {
            int col = j * 16 + r16;
            float bv = b12[col];
            float mv = 0.f;
#pragma unroll
            for (int i = 0; i < 2; ++i)
#pragma unroll
                for (int r = 0; r < 4; ++r)
                    mv = fmaxf(mv, acc[i][j][r] + bv);
            mv = fmaxf(mv, __shfl_xor(mv, 16));
            mv = fmaxf(mv, __shfl_xor(mv, 32));
            if (q == 0)
                f1[(size_t)((m0 >> 5) + w) * 128 + col] = f2bf(mv);
        }
    }
}

// ---------------- Module 2 fully fused: gather + L0(192) + L1(128) + L2(256)+pool ----
// R12: L1 weights (w21, 128x128) staged into R1 in ONE pass (fits: 128*136=17408<=18432),
// removing the per-K-tile restage + 2 barriers.
__global__ __launch_bounds__(256) void m2_kernel(
    const float* __restrict__ xyz1, const float* __restrict__ nxz2,
    const int* __restrict__ g2, const unsigned short* __restrict__ f1,
    const unsigned short* __restrict__ w20p, const float* __restrict__ b20,
    const unsigned short* __restrict__ w21b, const float* __restrict__ b21,
    const unsigned short* __restrict__ w22b, const float* __restrict__ b22,
    unsigned short* __restrict__ f2) {
    constexpr int AP = 72, HP = 136;
    __shared__ __align__(16) unsigned short smem[36864];   // 72 KB
    unsigned short* R1 = smem;
    unsigned short* R2 = smem + 18432;
    unsigned short* As = R1;
    unsigned short* Bs = R1 + 9216;
    unsigned short* W21 = R1;            // full w21, stride HP (17408 shorts)
    unsigned short* H1 = R2;
    unsigned short* H2 = R1;
    unsigned short* Bs2 = R2;
    __shared__ int ribase[128];
    __shared__ unsigned short sxb[128 * 3];
    const int t = threadIdx.x;
    const int lane = t & 63, w = t >> 6;
    const int r16 = lane & 15, q = lane >> 4;
    const int m0 = blockIdx.x * 128;

    if (t < 128) {
        int row = m0 + t, bs = row >> 5, b = bs >> 7, j = g2[row];
        ribase[t] = (b * 256 + j) * 128;
        const float* P = xyz1 + ((size_t)b * S1 + j) * 3;
        const float* Cc = nxz2 + (size_t)bs * 3;
        sxb[t * 3 + 0] = f2bf(P[0] - Cc[0]);
        sxb[t * 3 + 1] = f2bf(P[1] - Cc[1]);
        sxb[t * 3 + 2] = f2bf(P[2] - Cc[2]);
    }
    __syncthreads();

    // ---- L0: K=192 (3 tiles), N=128 ----
    f32x4 acc[2][8];
#pragma unroll
    for (int i = 0; i < 2; ++i)
#pragma unroll
        for (int j = 0; j < 8; ++j) acc[i][j] = (f32x4){0.f, 0.f, 0.f, 0.f};
    for (int kt = 0; kt < 3; ++kt) {
        const int k0 = kt * 64;
        if (kt < 2) {
            for (int c = t; c < 128 * 8; c += 256) {
                int row = c >> 3, ch = c & 7;
                *(short8*)&As[row * AP + ch * 8] =
                    *(const short8*)&f1[(size_t)ribase[row] + k0 + ch * 8];
            }
        } else {
            for (int c = t; c < 128 * 8; c += 256) {
                int row = c >> 3, ch = c & 7;
                short8 v = (short8){0, 0, 0, 0, 0, 0, 0, 0};
                if (ch == 0) {
                    v[0] = (short)sxb[row * 3 + 0];
                    v[1] = (short)sxb[row * 3 + 1];
                    v[2] = (short)sxb[row * 3 + 2];
                }
                *(short8*)&As[row * AP + ch * 8] = v;
            }
        }
        for (int c = t; c < 128 * 8; c += 256) {
            int row = c >> 3, ch = c & 7;
            *(short8*)&Bs[row * AP + ch * 8] =
                *(const short8*)&w20p[(size_t)row * 192 + k0 + ch * 8];
        }
        __syncthreads();
#pragma unroll
        for (int kk = 0; kk < 64; kk += 32) {
            short8 a0 = *(const short8*)&As[(w * 32 + r16) * AP + kk + q * 8];
            short8 a1 = *(const short8*)&As[(w * 32 + 16 + r16) * AP + kk + q * 8];
#pragma unroll
            for (int j = 0; j < 8; ++j) {
                short8 bf = *(const short8*)&Bs[(j * 16 + r16) * AP + kk + q * 8];
                acc[0][j] = __builtin_amdgcn_mfma_f32_16x16x32_bf16(a0, bf, acc[0][j], 0, 0, 0);
                acc[1][j] = __builtin_amdgcn_mfma_f32_16x16x32_bf16(a1, bf, acc[1][j], 0, 0, 0);
            }
        }
        __syncthreads();
    }
#pragma unroll
    for (int i = 0; i < 2; ++i)
#pragma unroll
        for (int j = 0; j < 8; ++j) {
            int col = j * 16 + r16;
            float bv = b20[col];
#pragma unroll
            for (int r = 0; r < 4; ++r) {
                int row = w * 32 + i * 16 + q * 4 + r;
                H1[row * HP + col] = f2bf(fmaxf(acc[i][j][r] + bv, 0.f));
            }
        }
    // ---- L1: K=128, N=128; stage FULL w21 into R1 (As/Bs dead), single barrier ----
    __syncthreads();
    for (int c = t; c < 128 * 16; c += 256) {
        int row = c >> 4, ch = c & 15;
        *(short8*)&W21[row * HP + ch * 8] =
            *(const short8*)&w21b[(size_t)row * 128 + ch * 8];
    }
    __syncthreads();
#pragma unroll
    for (int i = 0; i < 2; ++i)
#pragma unroll
        for (int j = 0; j < 8; ++j) acc[i][j] = (f32x4){0.f, 0.f, 0.f, 0.f};
#pragma unroll
    for (int kk = 0; kk < 128; kk += 32) {
        short8 a0 = *(const short8*)&H1[(w * 32 + r16) * HP + kk + q * 8];
        short8 a1 = *(const short8*)&H1[(w * 32 + 16 + r16) * HP + kk + q * 8];
#pragma unroll
        for (int j = 0; j < 8; ++j) {
            short8 bf = *(const short8*)&W21[(j * 16 + r16) * HP + kk + q * 8];
            acc[0][j] = __builtin_amdgcn_mfma_f32_16x16x32_bf16(a0, bf, acc[0][j], 0, 0, 0);
            acc[1][j] = __builtin_amdgcn_mfma_f32_16x16x32_bf16(a1, bf, acc[1][j], 0, 0, 0);
        }
    }
    __syncthreads();   // all waves done reading W21 (R1); H2 overwrites R1
#pragma unroll
    for (int i = 0; i < 2; ++i)
#pragma unroll
        for (int j = 0; j < 8; ++j) {
            int col = j * 16 + r16;
            float bv = b21[col];
#pragma unroll
            for (int r = 0; r < 4; ++r) {
                int row = w * 32 + i * 16 + q * 4 + r;
                H2[row * HP + col] = f2bf(fmaxf(acc[i][j][r] + bv, 0.f));
            }
        }
    __syncthreads();

    // ---- L2: K=128 (2 tiles), N=256 + pool ----
    f32x4 acc2[2][16];
#pragma unroll
    for (int i = 0; i < 2; ++i)
#pragma unroll
        for (int j = 0; j < 16; ++j) acc2[i][j] = (f32x4){0.f, 0.f, 0.f, 0.f};
    for (int kt = 0; kt < 2; ++kt) {
        const int k0 = kt * 64;
        for (int c = t; c < 256 * 8; c += 256) {
            int row = c >> 3, ch = c & 7;
            *(short8*)&Bs2[row * AP + ch * 8] =
                *(const short8*)&w22b[(size_t)row * 128 + k0 + ch * 8];
        }
        __syncthreads();
#pragma unroll
        for (int kk = 0; kk < 64; kk += 32) {
            short8 a0 = *(const short8*)&H2[(w * 32 + r16) * HP + k0 + kk + q * 8];
            short8 a1 = *(const short8*)&H2[(w * 32 + 16 + r16) * HP + k0 + kk + q * 8];
#pragma unroll
            for (int j = 0; j < 16; ++j) {
                short8 bf = *(const short8*)&Bs2[(j * 16 + r16) * AP + kk + q * 8];
                acc2[0][j] = __builtin_amdgcn_mfma_f32_16x16x32_bf16(a0, bf, acc2[0][j], 0, 0, 0);
                acc2[1][j] = __builtin_amdgcn_mfma_f32_16x16x32_bf16(a1, bf, acc2[1][j], 0, 0, 0);
            }
        }
        __syncthreads();
    }
#pragma unroll
    for (int j = 0; j < 16; ++j) {
        int col = j * 16 + r16;
        float bv = b22[col];
        float mv = 0.f;
#pragma unroll
        for (int i = 0; i < 2; ++i)
#pragma unroll
            for (int r = 0; r < 4; ++r)
                mv = fmaxf(mv, acc2[i][j][r] + bv);
        mv = fmaxf(mv, __shfl_xor(mv, 16));
        mv = fmaxf(mv, __shfl_xor(mv, 32));
        if (q == 0)
            f2[(size_t)((m0 >> 5) + w) * 256 + col] = f2bf(mv);
    }
}

// ---------------- Module 3 layer 0 with fused concat (feat-first K=320) ---------------
__global__ __launch_bounds__(256) void l30_kernel(
    const float* __restrict__ nxz2, const unsigned short* __restrict__ f2,
    const unsigned short* __restrict__ w30p, const float* __restrict__ bias,
    unsigned short* __restrict__ C) {
    constexpr int AP = 72;
    __shared__ __align__(16) unsigned short As[128 * AP];
    __shared__ __align__(16) unsigned short Bs[128 * AP];
    const int t = threadIdx.x;
    const int lane = t & 63, w = t >> 6;
    const int r16 = lane & 15, q = lane >> 4;
    const int m0 = blockIdx.x * 128;
    const int n0 = blockIdx.y * 128;

    f32x4 acc[2][8];
#pragma unroll
    for (int i = 0; i < 2; ++i)
#pragma unroll
        for (int j = 0; j < 8; ++j) acc[i][j] = (f32x4){0.f, 0.f, 0.f, 0.f};

    for (int kt = 0; kt < 5; ++kt) {
        const int k0 = kt * 64;
        if (kt < 4) {
            for (int c = t; c < 128 * 8; c += 256) {
                int row = c >> 3, ch = c & 7;
                *(short8*)&As[row * AP + ch * 8] =
                    *(const short8*)&f2[(size_t)(m0 + row) * 256 + k0 + ch * 8];
            }
        } else {
            for (int c = t; c < 128 * 8; c += 256) {
                int row = c >> 3, ch = c & 7;
                short8 v = (short8){0, 0, 0, 0, 0, 0, 0, 0};
                if (ch == 0) {
                    const float* P = nxz2 + (size_t)(m0 + row) * 3;
                    v[0] = (short)f2bf(P[0]);
                    v[1] = (short)f2bf(P[1]);
                    v[2] = (short)f2bf(P[2]);
                }
                *(short8*)&As[row * AP + ch * 8] = v;
            }
        }
        for (int c = t; c < 128 * 8; c += 256) {
            int row = c >> 3, ch = c & 7;
            *(short8*)&Bs[row * AP + ch * 8] =
                *(const short8*)&w30p[(size_t)(n0 + row) * 320 + k0 + ch * 8];
        }
        __syncthreads();
#pragma unroll
        for (int kk = 0; kk < 64; kk += 32) {
            short8 a0 = *(const short8*)&As[(w * 32 + r16) * AP + kk + q * 8];
            short8 a1 = *(const short8*)&As[(w * 32 + 16 + r16) * AP + kk + q * 8];
#pragma unroll
            for (int j = 0; j < 8; ++j) {
                short8 bf = *(const short8*)&Bs[(j * 16 + r16) * AP + kk + q * 8];
                acc[0][j] = __builtin_amdgcn_mfma_f32_16x16x32_bf16(a0, bf, acc[0][j], 0, 0, 0);
                acc[1][j] = __builtin_amdgcn_mfma_f32_16x16x32_bf16(a1, bf, acc[1][j], 0, 0, 0);
            }
        }
        __syncthreads();
    }
#pragma unroll
    for (int i = 0; i < 2; ++i)
#pragma unroll
        for (int j = 0; j < 8; ++j) {
            int col = n0 + j * 16 + r16;
            float bv = bias[col];
#pragma unroll
            for (int r = 0; r < 4; ++r) {
                int row = m0 + w * 32 + i * 16 + q * 4 + r;
                C[(size_t)row * 256 + col] = f2bf(fmaxf(acc[i][j][r] + bv, 0.f));
            }
        }
}

// ---------------- bf16 MFMA GEMM (BM templated): C = relu(X*W^T + bias), BN=128 --------
template <int BM_>
__global__ __launch_bounds__(256) void mfma_gemm(const unsigned short* __restrict__ X,
                                                 const unsigned short* __restrict__ W,
                                                 const float* __restrict__ bias,
                                                 unsigned short* __restrict__ C,
                                                 int M, int N, int K) {
    constexpr int BK = 64, AP = BK + 8;
    constexpr int RW = BM_ / 64;         // M-frags per wave
    constexpr int WR = BM_ / 4;          // rows per wave
    __shared__ __align__(16) unsigned short As[BM_ * AP];
    __shared__ __align__(16) unsigned short Bs[128 * AP];
    const int t = threadIdx.x;
    const int lane = t & 63, w = t >> 6;
    const int m0 = blockIdx.x * BM_;
    const int n0 = blockIdx.y * 128;
    const int r16 = lane & 15, q = lane >> 4;

    f32x4 acc[RW][8];
#pragma unroll
    for (int i = 0; i < RW; ++i)
#pragma unroll
        for (int j = 0; j < 8; ++j) acc[i][j] = (f32x4){0.f, 0.f, 0.f, 0.f};

    for (int k0 = 0; k0 < K; k0 += BK) {
        for (int c = t; c < BM_ * 8; c += 256) {
            int row = c >> 3, ch = c & 7;
            *(short8*)&As[row * AP + ch * 8] =
                *(const short8*)&X[(size_t)(m0 + row) * K + k0 + ch * 8];
        }
        for (int c = t; c < 128 * 8; c += 256) {
            int row = c >> 3, ch = c & 7;
            *(short8*)&Bs[row * AP + ch * 8] =
                *(const short8*)&W[(size_t)(n0 + row) * K + k0 + ch * 8];
        }
        __syncthreads();
#pragma unroll
        for (int kk = 0; kk < BK; kk += 32) {
            short8 a[RW];
#pragma unroll
            for (int i = 0; i < RW; ++i)
                a[i] = *(const short8*)&As[(w * WR + i * 16 + r16) * AP + kk + q * 8];
#pragma unroll
            for (int j = 0; j < 8; ++j) {
                short8 bf = *(const short8*)&Bs[(j * 16 + r16) * AP + kk + q * 8];
#pragma unroll
                for (int i = 0; i < RW; ++i)
                    acc[i][j] = __builtin_amdgcn_mfma_f32_16x16x32_bf16(a[i], bf, acc[i][j], 0, 0, 0);
            }
        }
        __syncthreads();
    }
#pragma unroll
    for (int i = 0; i < RW; ++i)
#pragma unroll
        for (int j = 0; j < 8; ++j) {
            int col = n0 + j * 16 + r16;
            float bv = bias[col];
#pragma unroll
            for (int r = 0; r < 4; ++r) {
                int row = m0 + w * WR + i * 16 + q * 4 + r;
                C[(size_t)row * N + col] = f2bf(fmaxf(acc[i][j][r] + bv, 0.f));
            }
        }
}

// ---------------- Final GEMM (N=1024, K=512) + max over 128 rows -> fp32 out ----------
__global__ __launch_bounds__(256) void gemm_pool128(const unsigned short* __restrict__ X,
                                                    const unsigned short* __restrict__ W,
                                                    const float* __restrict__ bias,
                                                    float* __restrict__ out) {
    constexpr int BK = 64, AP = BK + 8, K = 512;
    __shared__ __align__(16) unsigned short As[128 * AP];
    __shared__ __align__(16) unsigned short Bs[128 * AP];
    __shared__ float pool[4][128];
    const int t = threadIdx.x;
    const int lane = t & 63, w = t >> 6;
    const int m0 = blockIdx.x * 128;
    const int n0 = blockIdx.y * 128;
    const int r16 = lane & 15, q = lane >> 4;

    f32x4 acc[2][8];
#pragma unroll
    for (int i = 0; i < 2; ++i)
#pragma unroll
        for (int j = 0; j < 8; ++j) acc[i][j] = (f32x4){0.f, 0.f, 0.f, 0.f};

    for (int k0 = 0; k0 < K; k0 += BK) {
        for (int c = t; c < 128 * 8; c += 256) {
            int row = c >> 3, ch = c & 7;
            *(short8*)&As[row * AP + ch * 8] =
                *(const short8*)&X[(size_t)(m0 + row) * K + k0 + ch * 8];
        }
        for (int c = t; c < 128 * 8; c += 256) {
            int row = c >> 3, ch = c & 7;
            *(short8*)&Bs[row * AP + ch * 8] =
                *(const short8*)&W[(size_t)(n0 + row) * K + k0 + ch * 8];
        }
        __syncthreads();
#pragma unroll
        for (int kk = 0; kk < BK; kk += 32) {
            short8 a0 = *(const short8*)&As[(w * 32 + r16) * AP + kk + q * 8];
            short8 a1 = *(const short8*)&As[(w * 32 + 16 + r16) * AP + kk + q * 8];
#pragma unroll
            for (int j = 0; j < 8; ++j) {
                short8 bf = *(const short8*)&Bs[(j * 16 + r16) * AP + kk + q * 8];
                acc[0][j] = __builtin_amdgcn_mfma_f32_16x16x32_bf16(a0, bf, acc[0][j], 0, 0, 0);
                acc[1][j] = __builtin_amdgcn_mfma_f32_16x16x32_bf16(a1, bf, acc[1][j], 0, 0, 0);
            }
        }
        __syncthreads();
    }
    // wave-level pool over its 32 rows (relu via 0-init), then cross-wave via LDS
#pragma unroll
    for (int j = 0; j < 8; ++j) {
        float bv = bias[n0 + j * 16 + r16];
        float mv = 0.f;
#pragma unroll
        for (int i = 0; i < 2; ++i)
#pragma unroll
            for (int r = 0; r < 4; ++r)
                mv = fmaxf(mv, acc[i][j][r] + bv);
        mv = fmaxf(mv, __shfl_xor(mv, 16));
        mv = fmaxf(mv, __shfl_xor(mv, 32));
        if (q == 0) pool[w][j * 16 + r16] = mv;
    }
    __syncthreads();
    if (t < 128) {
        float m = fmaxf(fmaxf(pool[0][t], pool[1][t]), fmaxf(pool[2][t], pool[3][t]));
        out[(size_t)blockIdx.x * 1024 + n0 + t] = m;
    }
}

extern "C" void kernel_launch(void* const* d_in, const int* in_sizes, int n_in,
                              void* d_out, int out_size, void* d_ws, size_t ws_size,
                              hipStream_t stream) {
    const float* data = (const float*)d_in[0];
    const float* w10 = (const float*)d_in[1];  const float* b10 = (const float*)d_in[2];
    const float* w11 = (const float*)d_in[3];  const float* b11 = (const float*)d_in[4];
    const float* w12 = (const float*)d_in[5];  const float* b12 = (const float*)d_in[6];
    const float* w20 = (const float*)d_in[7];  const float* b20 = (const float*)d_in[8];
    const float* w21 = (const float*)d_in[9];  const float* b21 = (const float*)d_in[10];
    const float* w22 = (const float*)d_in[11]; const float* b22 = (const float*)d_in[12];
    const float* w30 = (const float*)d_in[13]; const float* b30 = (const float*)d_in[14];
    const float* w31 = (const float*)d_in[15]; const float* b31 = (const float*)d_in[16];
    const float* w32 = (const float*)d_in[17]; const float* b32 = (const float*)d_in[18];
    float* out = (float*)d_out;

    char* ws = (char*)d_ws;
    size_t off = 0;
    auto alloc = [&](size_t bytes) -> void* {
        void* p = ws + off;
        off += (bytes + 255) & ~(size_t)255;
        return p;
    };
    float* nxz1 = (float*)alloc((size_t)BT * S1 * 3 * 4);
    int*   g1   = (int*)  alloc((size_t)BT * S1 * KNB * 4);
    float* nxz2 = (float*)alloc((size_t)BT * S2 * 3 * 4);
    int*   g2   = (int*)  alloc((size_t)BT * S2 * KNB * 4);
    unsigned short* wb  = (unsigned short*)alloc((size_t)823296 * 2);
    unsigned short* f1  = (unsigned short*)alloc((size_t)8192 * 128 * 2);
    unsigned short* f2  = (unsigned short*)alloc((size_t)4096 * 256 * 2);
    unsigned short* C1  = (unsigned short*)alloc((size_t)4096 * 256 * 2);
    unsigned short* C2  = (unsigned short*)alloc((size_t)4096 * 512 * 2);

    const unsigned short* w11b = wb + 0;
    const unsigned short* w12b = wb + 4096;
    const unsigned short* w20p = wb + 12288;
    const unsigned short* w21b = wb + 36864;
    const unsigned short* w22b = wb + 53248;
    const unsigned short* w30p = wb + 86016;
    const unsigned short* w31b = wb + 167936;
    const unsigned short* w32b = wb + 299008;

    wconv_kernel<<<(823296 + 255) / 256, 256, 0, stream>>>(w11, w12, w20, w21, w22, w30, w31, w32, wb);

    // ---- module 1 ----
    fps1_kernel<<<BT, 256, 0, stream>>>(data, nxz1);
    ballq1_kernel<<<(BT * S1) / 4, 256, 0, stream>>>(data, nxz1, g1);
    m1_kernel<<<262144 / 128, 256, 0, stream>>>(data, nxz1, g1, w10, b10, w11b, b11, w12b, b12, f1);
    // ---- module 2 ----
    fps2_kernel<<<BT, 64, 0, stream>>>(nxz1, nxz2);
    ballq2_kernel<<<(BT * S2) / 4, 256, 0, stream>>>(nxz1, nxz2, g2);
    m2_kernel<<<131072 / 128, 256, 0, stream>>>(nxz1, nxz2, g2, f1, w20p, b20, w21b, b21, w22b, b22, f2);
    // ---- module 3 ----
    l30_kernel<<<dim3(4096 / 128, 2), 256, 0, stream>>>(nxz2, f2, w30p, b30, C1);
    mfma_gemm<64><<<dim3(4096 / 64, 4), 256, 0, stream>>>(C1, w31b, b31, C2, 4096, 512, 256);
    gemm_pool128<<<dim3(4096 / 128, 8), 256, 0, stream>>>(C2, w32b, b32, out);
}